// Round 13
// baseline (494.013 us; speedup 1.0000x reference)
//
#include <hip/hip_runtime.h>

typedef __attribute__((ext_vector_type(4))) unsigned short us4;
typedef __attribute__((ext_vector_type(8))) unsigned short us8;
typedef __attribute__((ext_vector_type(8))) short s8;      // MFMA A/B fragment (8 bf16)
typedef __attribute__((ext_vector_type(4))) float f32x4;   // 16x16 MFMA acc / float4
typedef __attribute__((ext_vector_type(16))) float f32x16; // 32x32 MFMA acc

#define NTOK 32768
#define DIM_ 1024
#define HEADS_ 8
#define DH_ 64
#define WS_ 256
#define NWIN_ 128
#define INNER_ 512

__device__ __forceinline__ float b2f(unsigned short u) {
  union { unsigned u; float f; } x; x.u = ((unsigned)u) << 16; return x.f;
}
__device__ __forceinline__ unsigned short f2b(float f) {
  union { float f; unsigned u; } x; x.f = f;
  unsigned r = x.u + 0x7FFFu + ((x.u >> 16) & 1u);  // RNE
  return (unsigned short)(r >> 16);
}
__device__ __forceinline__ unsigned pk2(float a, float b) {
  return (unsigned)f2b(a) | ((unsigned)f2b(b) << 16);
}
__device__ __forceinline__ s8 mk_s8(unsigned w0, unsigned w1, unsigned w2, unsigned w3) {
  union { unsigned u[4]; s8 v; } x;
  x.u[0] = w0; x.u[1] = w1; x.u[2] = w2; x.u[3] = w3;
  return x.v;
}

// global -> LDS direct DMA, 16B per lane. LDS dest = wave-uniform base + lane*16.
__device__ __forceinline__ void gload_lds16(const unsigned short* g, void* l) {
  __builtin_amdgcn_global_load_lds((const __attribute__((address_space(1))) void*)g,
                                   (__attribute__((address_space(3))) void*)l, 16, 0, 0);
}

// ---------------------------------------------------------------------------
// LayerNorm (f32 in) + half-row shift -> bf16 xs.
// ---------------------------------------------------------------------------
__global__ __launch_bounds__(256) void ln_shift(const float* __restrict__ x,
                                                const float* __restrict__ gamma,
                                                const float* __restrict__ beta,
                                                unsigned short* __restrict__ xs) {
  int row = blockIdx.x;
  int t = threadIdx.x;
  f32x4 v = ((const f32x4*)(x + (size_t)row * DIM_))[t];
  float sum = 0.f, ss = 0.f;
#pragma unroll
  for (int j = 0; j < 4; j++) { sum += v[j]; ss += v[j] * v[j]; }
#pragma unroll
  for (int off = 32; off >= 1; off >>= 1) {
    sum += __shfl_xor(sum, off);
    ss  += __shfl_xor(ss, off);
  }
  __shared__ float red[2][4];
  int wave = t >> 6, l = t & 63;
  if (l == 0) { red[0][wave] = sum; red[1][wave] = ss; }
  __syncthreads();
  sum = red[0][0] + red[0][1] + red[0][2] + red[0][3];
  ss  = red[1][0] + red[1][1] + red[1][2] + red[1][3];
  float mu = sum * (1.0f / DIM_);
  float var = ss * (1.0f / DIM_) - mu * mu;
  float rs = rsqrtf(var + 1e-5f);
  f32x4 g = ((const f32x4*)gamma)[t];
  f32x4 bb = ((const f32x4*)beta)[t];
  us4 o;
#pragma unroll
  for (int j = 0; j < 4; j++) o[j] = f2b((v[j] - mu) * rs * g[j] + bb[j]);
  int c0 = t * 4;
  if (c0 >= 512) {
    *(us4*)(xs + (size_t)row * DIM_ + c0) = o;
  } else {
    if (row + 1 < NTOK) *(us4*)(xs + (size_t)(row + 1) * DIM_ + c0) = o;
    if (row == 0) { us4 z = {0, 0, 0, 0}; *(us4*)(xs + c0) = z; }
  }
}

// ---------------------------------------------------------------------------
// f32 (R,C) -> bf16 (C,R) transpose; R,C multiples of 32. block (32,8)
// ---------------------------------------------------------------------------
__global__ __launch_bounds__(256) void transpose_f32_bf16(const float* __restrict__ in,
                                                          unsigned short* __restrict__ out,
                                                          int R, int C) {
  __shared__ unsigned short tile[32][33];
  int bx = blockIdx.x * 32, by = blockIdx.y * 32;
  int tx = threadIdx.x, ty = threadIdx.y;
#pragma unroll
  for (int i = 0; i < 32; i += 8) tile[ty + i][tx] = f2b(in[(size_t)(by + ty + i) * C + bx + tx]);
  __syncthreads();
#pragma unroll
  for (int i = 0; i < 32; i += 8) out[(size_t)(bx + ty + i) * R + by + tx] = tile[tx][ty + i];
}

// ---------------------------------------------------------------------------
// One BK=64 K-tile: issue A(kt+1)->LDS + B(kt+1)->regs, 4 phases x 16 MFMA
// using B from registers (bu), then vmcnt(0) + single barrier.
// ---------------------------------------------------------------------------
__device__ __forceinline__ void gemm_tile_body(int kt, int nk, char* lds,
                                               const unsigned short* gA,
                                               const unsigned short* gB0,
                                               const unsigned short* gB1,
                                               const unsigned short* gB2,
                                               const unsigned short* gB3,
                                               int K, int t16,
                                               f32x4 (&acc)[8][4],
                                               s8 (&bu)[8], s8 (&bn)[8],
                                               int wm, int ll, int lg) {
  const char* sa = lds + (kt & 1) * 32768;
  __builtin_amdgcn_sched_barrier(0);
  if (kt + 1 < nk) {
    // A(kt+1) -> other LDS slot (DMA, HBM-latency: issue first)
    char* dA = lds + ((kt + 1) & 1) * 32768;
    const unsigned short* nA = gA + (kt + 1) * 64;
#pragma unroll
    for (int j = 0; j < 4; j++) gload_lds16(nA + (size_t)(j * 64) * K, dA + j * 8192 + t16);
    // B(kt+1) -> registers (per-lane gather from L2-resident panel)
    int c = (kt + 1) * 64;
    bn[0] = *(const s8*)(gB0 + c);  bn[4] = *(const s8*)(gB0 + c + 32);
    bn[1] = *(const s8*)(gB1 + c);  bn[5] = *(const s8*)(gB1 + c + 32);
    bn[2] = *(const s8*)(gB2 + c);  bn[6] = *(const s8*)(gB2 + c + 32);
    bn[3] = *(const s8*)(gB3 + c);  bn[7] = *(const s8*)(gB3 + c + 32);
  }
  __builtin_amdgcn_sched_barrier(0);
#pragma unroll
  for (int p = 0; p < 4; ++p) {
    const int qm = p & 1, kk = p >> 1;
    s8 af[4];
#pragma unroll
    for (int m = 0; m < 4; m++) {
      int r = wm * 128 + qm * 64 + m * 16 + ll;
      af[m] = *(const s8*)(sa + r * 128 + (((kk * 4 + lg) ^ (r & 7)) << 4));
    }
    __builtin_amdgcn_s_setprio(1);
#pragma unroll
    for (int m = 0; m < 4; m++)
#pragma unroll
      for (int n = 0; n < 4; n++)
        acc[qm * 4 + m][n] =
            __builtin_amdgcn_mfma_f32_16x16x32_bf16(af[m], bu[kk * 4 + n], acc[qm * 4 + m][n], 0, 0, 0);
    __builtin_amdgcn_s_setprio(0);
  }
  if (kt + 1 < nk) asm volatile("s_waitcnt vmcnt(0)" ::: "memory");
  __builtin_amdgcn_sched_barrier(0);
  __builtin_amdgcn_s_barrier();
  __builtin_amdgcn_sched_barrier(0);
}

// ---------------------------------------------------------------------------
// NT GEMM p13 (B-in-registers): C[M,N] = A[M,K] @ Bt[N,K]^T.
// BM=BN=256, BK=64, 512 thr (8 waves 2Mx4N, wave tile 128x64).
// A: global_load_lds, 2-slot dbuf (64 KiB). B: per-wave register double
// buffer loaded directly from the L2/L3-resident Bt panel — removes B's
// LDS reads AND stage-writes (the LDS pipe was the measured 26-34%
// MfmaUtil ceiling: 256KB LDS traffic/block-tile vs 614cyc MFMA).
// One barrier + vmcnt(0) per tile.
// NOTE: __launch_bounds__(512,2) REQUIRED — acc(128)+B regs(64) unified;
// min-4 bound would spill (round 7: 8x slower).
// MODE 0: RoPE epilogue -> qh/kh (lane-quad transpose) + vt (lane-pair shfl,
// direct-transposed us4). MODE 1: f32 C + bias.
// ---------------------------------------------------------------------------
template <int MODE>
__global__ __launch_bounds__(512, 2) void gemm_p13(const unsigned short* __restrict__ A,
                                                   const unsigned short* __restrict__ Bt,
                                                   void* __restrict__ Cv,
                                                   const float* __restrict__ bias,
                                                   const float* __restrict__ sinp,
                                                   const float* __restrict__ cosp,
                                                   unsigned short* __restrict__ qh,
                                                   unsigned short* __restrict__ kh,
                                                   unsigned short* __restrict__ vt,
                                                   int M, int N, int K) {
  __shared__ __align__(16) char lds[65536];   // A slots 0/1 @ s*32768
  int t = threadIdx.x;
  int l = t & 63, lg = l >> 4, ll = l & 15;
  int wave = t >> 6;
  int wm = wave >> 2, wn = wave & 3;

  // XCD-bijective flat block swizzle (nwg % 8 == 0 for all our grids)
  int nbx = gridDim.x;
  int nwg = nbx * gridDim.y;
  int flat = blockIdx.y * nbx + blockIdx.x;
  int swz = (flat & 7) * (nwg >> 3) + (flat >> 3);
  int m0 = (swz / nbx) * 256, n0 = (swz % nbx) * 256;

  const f32x4 fz = {0.f, 0.f, 0.f, 0.f};
  f32x4 acc[8][4];
#pragma unroll
  for (int m = 0; m < 8; m++)
#pragma unroll
    for (int n = 0; n < 4; n++) acc[m][n] = fz;

  // A staging: issue j covers rows j*64 + (t>>3), unit (t&7)^(row&7); 8KB/issue
  int srow = t >> 3;                           // 0..63
  int sunit = (t & 7) ^ (srow & 7);            // pre-swizzled source 16B-unit
  const unsigned short* gA = A + (size_t)(m0 + srow) * K + sunit * 8;
  int t16 = t * 16;
  int nk = K >> 6;

  // B register-load bases: row (n0 + wn*64 + n*16 + ll), col lg*8
  const unsigned short* gB0 = Bt + (size_t)(n0 + wn * 64 + ll) * K + lg * 8;
  const unsigned short* gB1 = gB0 + (size_t)16 * K;
  const unsigned short* gB2 = gB0 + (size_t)32 * K;
  const unsigned short* gB3 = gB0 + (size_t)48 * K;

  s8 b0[8], b1[8];

  // prologue: A(0)->slot0 (DMA), B(0)->b0 (regs)
#pragma unroll
  for (int j = 0; j < 4; j++) gload_lds16(gA + (size_t)(j * 64) * K, lds + j * 8192 + t16);
  b0[0] = *(const s8*)(gB0);  b0[4] = *(const s8*)(gB0 + 32);
  b0[1] = *(const s8*)(gB1);  b0[5] = *(const s8*)(gB1 + 32);
  b0[2] = *(const s8*)(gB2);  b0[6] = *(const s8*)(gB2 + 32);
  b0[3] = *(const s8*)(gB3);  b0[7] = *(const s8*)(gB3 + 32);
  asm volatile("s_waitcnt vmcnt(0)" ::: "memory");
  __builtin_amdgcn_sched_barrier(0);
  __builtin_amdgcn_s_barrier();
  __builtin_amdgcn_sched_barrier(0);

  for (int kt2 = 0; kt2 < nk; kt2 += 2) {
    gemm_tile_body(kt2, nk, lds, gA, gB0, gB1, gB2, gB3, K, t16, acc, b0, b1, wm, ll, lg);
    gemm_tile_body(kt2 + 1, nk, lds, gA, gB0, gB1, gB2, gB3, K, t16, acc, b1, b0, wm, ll, lg);
  }

  if (MODE == 0) {
    int third = n0 >> 9;  // block-uniform: 0=q, 1=k, 2=v
    if (third == 2) {
      // v: pre-transpose each lane holds rows lg*4..+3 (tokens) of col d.
      // RoPE partner (d^1) is lane ll^1 -> one shfl_xor per element.
      bool odd = (ll & 1) != 0;
#pragma unroll
      for (int m = 0; m < 8; m++) {
        int row0 = m0 + wm * 128 + m * 16 + lg * 4;
#pragma unroll
        for (int n = 0; n < 4; n++) {
          int cit = (n0 - 1024) + wn * 64 + n * 16 + ll;
          int head = cit >> 6, d = cit & 63;
          us4 st;
#pragma unroll
          for (int r = 0; r < 4; r++) {
            float v = acc[m][n][r];
            float p = __shfl_xor(v, 1);
            float sn = sinp[(size_t)(row0 + r) * 64 + d];
            float cs = cosp[(size_t)(row0 + r) * 64 + d];
            st[r] = f2b(odd ? (v * cs + p * sn) : (v * cs - p * sn));
          }
          *(us4*)(vt + ((size_t)head * 64 + d) * NTOK + row0) = st;
        }
      }
    } else {
      // q/k: 4x4 lane-quad transpose -> lane holds (row = lg*4+b, cols q*4..+3);
      // RoPE pairs lane-local; coalesced us4 stores.
      int b = ll & 3, q = ll >> 2;
      bool bo1 = (b & 1) != 0, bo2 = (b & 2) != 0;
#pragma unroll
      for (int m = 0; m < 8; m++) {
        int row = m0 + wm * 128 + m * 16 + lg * 4 + b;  // token
#pragma unroll
        for (int n = 0; n < 4; n++) {
          float v0 = acc[m][n][0], v1 = acc[m][n][1], v2 = acc[m][n][2], v3 = acc[m][n][3];
          float x0 = __shfl_xor(v1, 1);
          float x1 = __shfl_xor(v0, 1);
          float x2 = __shfl_xor(v3, 1);
          float x3 = __shfl_xor(v2, 1);
          float u0 = bo1 ? x0 : v0;
          float u1 = bo1 ? v1 : x1;
          float u2 = bo1 ? x2 : v2;
          float u3 = bo1 ? v3 : x3;
          float y0 = __shfl_xor(u2, 2);
          float y1 = __shfl_xor(u3, 2);
          float y2 = __shfl_xor(u0, 2);
          float y3 = __shfl_xor(u1, 2);
          float w0 = bo2 ? y0 : u0;
          float w1 = bo2 ? y1 : u1;
          float w2 = bo2 ? u2 : y2;
          float w3 = bo2 ? u3 : y3;
          int cb = n0 + wn * 64 + n * 16 + q * 4;
          int cit = cb & 511;
          int head = cit >> 6, d0 = cit & 63;
          f32x4 s4 = *(const f32x4*)(sinp + (size_t)row * 64 + d0);
          f32x4 c4 = *(const f32x4*)(cosp + (size_t)row * 64 + d0);
          us4 st;
          st[0] = f2b(w0 * c4[0] - w1 * s4[0]);
          st[1] = f2b(w1 * c4[1] + w0 * s4[1]);
          st[2] = f2b(w2 * c4[2] - w3 * s4[2]);
          st[3] = f2b(w3 * c4[3] + w2 * s4[3]);
          if (third == 0) *(us4*)(qh + ((size_t)head * NTOK + row) * 64 + d0) = st;
          else            *(us4*)(kh + ((size_t)head * NTOK + row) * 64 + d0) = st;
        }
      }
    }
  } else {
#pragma unroll
    for (int n = 0; n < 4; n++) {
      int col = n0 + wn * 64 + n * 16 + ll;
      float bs = bias ? bias[col] : 0.0f;
#pragma unroll
      for (int m = 0; m < 8; m++) {
#pragma unroll
        for (int r = 0; r < 4; r++) {
          int row = m0 + wm * 128 + m * 16 + lg * 4 + r;
          ((float*)Cv)[(size_t)row * N + col] = acc[m][n][r] + bs;
        }
      }
    }
  }
}

// ---------------------------------------------------------------------------
// Windowed lookback attention, v3: 32x32 MFMA, swapped operands.
// block = (half, window, head), 4 waves x 32 q-rows. 8 chunks of 64 keys.
// ---------------------------------------------------------------------------
__global__ __launch_bounds__(256, 4) void attn_kernel(const unsigned short* __restrict__ qh,
                                                      const unsigned short* __restrict__ kh,
                                                      const unsigned short* __restrict__ vt,
                                                      unsigned short* __restrict__ ao) {
  __shared__ char kbuf[2][8192];   // 64 keys x 128B, unit-swizzled by (row&7)
  __shared__ char vbuf[8192];      // 64 d x 128B (64 keys), unit-swizzled by (d&7)
  int half = blockIdx.x, w = blockIdx.y, h = blockIdx.z;
  int t = threadIdx.x;
  int wave = t >> 6, l = t & 63;
  int l31 = l & 31, hi = l >> 5;
  const unsigned short* qb = qh + (size_t)h * NTOK * 64;
  const unsigned short* kb = kh + (size_t)h * NTOK * 64;
  const unsigned short* vb = vt + (size_t)h * 64 * NTOK;

  int qw = half * 128 + wave * 32 + l31;   // q within window
  int qn = w * 256 + qw;                   // global token
  s8 qf[4];
#pragma unroll
  for (int dht = 0; dht < 4; dht++)
    qf[dht] = *(const s8*)(qb + (size_t)qn * 64 + dht * 16 + hi * 8);

  f32x16 o0 = {}, o1 = {};
  float dsum = (w == 0) ? 128.f : 0.f;     // 256 zero-keys -> exp(0)=1, split across hi halves
  int n0 = w * 256 - 256;
  int c0 = (w == 0) ? 4 : 0;

  int srow = wave * 16 + (l >> 3);
  int sunit = l & 7;

  // prologue: stage K(c0)
  {
    const unsigned short* g = kb + (size_t)(n0 + c0 * 64 + srow) * 64 + ((sunit ^ (srow & 7)) * 8);
    gload_lds16(g, kbuf[c0 & 1] + wave * 2048);
    gload_lds16(g + 8 * 64, kbuf[c0 & 1] + wave * 2048 + 1024);
  }
  __syncthreads();

  for (int c = c0; c < 8; ++c) {
    int cb = n0 + c * 64;
    // stage V(c)
    {
      int d = srow;
      const unsigned short* g = vb + (size_t)d * NTOK + cb + ((sunit ^ (d & 7)) * 8);
      gload_lds16(g, vbuf + wave * 2048);
      gload_lds16(g + (size_t)8 * NTOK, vbuf + wave * 2048 + 1024);
    }
    // stage K(c+1)
    if (c < 7) {
      const unsigned short* g = kb + (size_t)(cb + 64 + srow) * 64 + ((sunit ^ (srow & 7)) * 8);
      gload_lds16(g, kbuf[(c + 1) & 1] + wave * 2048);
      gload_lds16(g + 8 * 64, kbuf[(c + 1) & 1] + wave * 2048 + 1024);
    }

    // QK^T (swapped): S^T tiles, 64 keys x 32 q
    f32x16 s[2] = {{}, {}};
    const char* kl = kbuf[c & 1];
#pragma unroll
    for (int kt = 0; kt < 2; kt++) {
#pragma unroll
      for (int dht = 0; dht < 4; dht++) {
        int row = kt * 32 + l31;
        int unit = (dht * 2 + hi) ^ (row & 7);
        s8 kf = *(const s8*)(kl + row * 128 + unit * 16);
        s[kt] = __builtin_amdgcn_mfma_f32_32x32x16_bf16(kf, qf[dht], s[kt], 0, 0, 0);
      }
    }

    // masked exp (no max-sub) + denominator + pack to bf16 pairs
    unsigned P0[2][4], P1[2][4];
#pragma unroll
    for (int kt = 0; kt < 2; kt++) {
#pragma unroll
      for (int r = 0; r < 16; r++) {
        int j = c * 64 + kt * 32 + (r & 3) + 8 * (r >> 2) + hi * 4;
        float e = (j <= qw + 256) ? __expf(s[kt][r] * 0.125f) : 0.f;
        s[kt][r] = e;
        dsum += e;
      }
#pragma unroll
      for (int j2 = 0; j2 < 4; j2++) {
        P0[kt][j2] = pk2(s[kt][j2 * 4 + 0], s[kt][j2 * 4 + 1]);
        P1[kt][j2] = pk2(s[kt][j2 * 4 + 2], s[kt][j2 * 4 + 3]);
      }
    }

    __syncthreads();   // V(c) staged (drains K(c+1) too)

    // PV (swapped): O^T += V^T(chunk) . P^T(chunk)
#pragma unroll
    for (int tt = 0; tt < 4; tt++) {
      int kt = tt >> 1, ss = tt & 1;
      unsigned a = P0[kt][2 * ss], b = P1[kt][2 * ss];
      unsigned cx = P0[kt][2 * ss + 1], dx = P1[kt][2 * ss + 1];
      asm volatile("v_permlane32_swap_b32 %0, %1" : "+v"(a), "+v"(cx));
      asm volatile("v_permlane32_swap_b32 %0, %1" : "+v"(b), "+v"(dx));
      s8 pf = mk_s8(a, b, cx, dx);
      {
        int row = l31;
        int unit = (tt * 2 + hi) ^ (row & 7);
        s8 vf = *(const s8*)(vbuf + row * 128 + unit * 16);
        o0 = __builtin_amdgcn_mfma_f32_32x32x16_bf16(vf, pf, o0, 0, 0, 0);
      }
      {
        int row = 32 + l31;
        int unit = (tt * 2 + hi) ^ (row & 7);
        s8 vf = *(const s8*)(vbuf + row * 128 + unit * 16);
        o1 = __builtin_amdgcn_mfma_f32_32x32x16_bf16(vf, pf, o1, 0, 0, 0);
      }
    }
    __syncthreads();   // LDS consumed; next iter may overwrite
  }

  dsum += __shfl_xor(dsum, 32);
  float inv = 1.f / dsum;

  unsigned short* orow = ao + (size_t)qn * INNER_ + h * 64;
#pragma unroll
  for (int g = 0; g < 4; g++) {
    us4 st0, st1;
#pragma unroll
    for (int rr = 0; rr < 4; rr++) {
      st0[rr] = f2b(o0[g * 4 + rr] * inv);
      st1[rr] = f2b(o1[g * 4 + rr] * inv);
    }
    *(us4*)(orow + g * 8 + hi * 4) = st0;
    *(us4*)(orow + 32 + g * 8 + hi * 4) = st1;
  }
}

// ---------------------------------------------------------------------------
extern "C" void kernel_launch(void* const* d_in, const int* in_sizes, int n_in,
                              void* d_out, int out_size, void* d_ws, size_t ws_size,
                              hipStream_t stream) {
  const float* x     = (const float*)d_in[0];
  const float* sin_  = (const float*)d_in[1];
  const float* cos_  = (const float*)d_in[2];
  const float* gamma = (const float*)d_in[3];
  const float* beta  = (const float*)d_in[4];
  const float* w_qkv = (const float*)d_in[5];
  const float* w_out = (const float*)d_in[6];
  const float* b_out = (const float*)d_in[7];

  // ws layout (bytes). total needed = 171,966,464
  char* ws = (char*)d_ws;
  const size_t OFF_WQT = 0;                    // 1536*1024*2 = 3,145,728
  const size_t OFF_WOT = 3145728;              // 1024*512*2  = 1,048,576
  const size_t OFF_XS  = 4194304;              // 32768*1024*2 = 67,108,864 (xs; later ao)
  const size_t OFF_QH  = 71303168;             // 8*32768*64*2 = 33,554,432
  const size_t OFF_KH  = 104857600;            // 33,554,432
  const size_t OFF_VT  = 138412032;            // 8*64*32768*2 = 33,554,432
  const size_t NEEDED  = 171966464;
  if (ws_size < NEEDED) return;  // fail loudly (output stays poisoned)

  unsigned short* wqT = (unsigned short*)(ws + OFF_WQT);
  unsigned short* woT = (unsigned short*)(ws + OFF_WOT);
  unsigned short* xs  = (unsigned short*)(ws + OFF_XS);
  unsigned short* qh  = (unsigned short*)(ws + OFF_QH);
  unsigned short* kh  = (unsigned short*)(ws + OFF_KH);
  unsigned short* vt  = (unsigned short*)(ws + OFF_VT);
  unsigned short* ao  = xs;   // xs dead after gemm1; attn writes ao here

  transpose_f32_bf16<<<dim3(1536 / 32, 1024 / 32), dim3(32, 8), 0, stream>>>(w_qkv, wqT, 1024, 1536);
  transpose_f32_bf16<<<dim3(1024 / 32, 512 / 32), dim3(32, 8), 0, stream>>>(w_out, woT, 512, 1024);
  ln_shift<<<NTOK, 256, 0, stream>>>(x, gamma, beta, xs);
  gemm_p13<0><<<dim3(1536 / 256, NTOK / 256), 512, 0, stream>>>(
      xs, wqT, nullptr, nullptr, sin_, cos_, qh, kh, vt, NTOK, 1536, 1024);
  attn_kernel<<<dim3(2, NWIN_, HEADS_), 256, 0, stream>>>(qh, kh, vt, ao);
  gemm_p13<1><<<dim3(1024 / 256, NTOK / 256), 512, 0, stream>>>(
      ao, woT, (void*)d_out, b_out, nullptr, nullptr, nullptr, nullptr, nullptr, NTOK, 1024, 512);
}

// Round 14
// 487.685 us; speedup vs baseline: 1.0130x; 1.0130x over previous
//
#include <hip/hip_runtime.h>

typedef __attribute__((ext_vector_type(4))) unsigned short us4;
typedef __attribute__((ext_vector_type(8))) unsigned short us8;
typedef __attribute__((ext_vector_type(8))) short s8;      // MFMA A/B fragment (8 bf16)
typedef __attribute__((ext_vector_type(4))) float f32x4;   // 16x16 MFMA acc / float4
typedef __attribute__((ext_vector_type(16))) float f32x16; // 32x32 MFMA acc

#define NTOK 32768
#define DIM_ 1024
#define HEADS_ 8
#define DH_ 64
#define WS_ 256
#define NWIN_ 128
#define INNER_ 512

__device__ __forceinline__ float b2f(unsigned short u) {
  union { unsigned u; float f; } x; x.u = ((unsigned)u) << 16; return x.f;
}
__device__ __forceinline__ unsigned short f2b(float f) {
  union { float f; unsigned u; } x; x.f = f;
  unsigned r = x.u + 0x7FFFu + ((x.u >> 16) & 1u);  // RNE
  return (unsigned short)(r >> 16);
}
__device__ __forceinline__ unsigned pk2(float a, float b) {
  return (unsigned)f2b(a) | ((unsigned)f2b(b) << 16);
}
__device__ __forceinline__ s8 mk_s8(unsigned w0, unsigned w1, unsigned w2, unsigned w3) {
  union { unsigned u[4]; s8 v; } x;
  x.u[0] = w0; x.u[1] = w1; x.u[2] = w2; x.u[3] = w3;
  return x.v;
}

// global -> LDS direct DMA, 16B per lane. LDS dest = wave-uniform base + lane*16.
__device__ __forceinline__ void gload_lds16(const unsigned short* g, void* l) {
  __builtin_amdgcn_global_load_lds((const __attribute__((address_space(1))) void*)g,
                                   (__attribute__((address_space(3))) void*)l, 16, 0, 0);
}

// ---------------------------------------------------------------------------
// LayerNorm (f32 in) + half-row shift -> bf16 xs.
// ---------------------------------------------------------------------------
__global__ __launch_bounds__(256) void ln_shift(const float* __restrict__ x,
                                                const float* __restrict__ gamma,
                                                const float* __restrict__ beta,
                                                unsigned short* __restrict__ xs) {
  int row = blockIdx.x;
  int t = threadIdx.x;
  f32x4 v = ((const f32x4*)(x + (size_t)row * DIM_))[t];
  float sum = 0.f, ss = 0.f;
#pragma unroll
  for (int j = 0; j < 4; j++) { sum += v[j]; ss += v[j] * v[j]; }
#pragma unroll
  for (int off = 32; off >= 1; off >>= 1) {
    sum += __shfl_xor(sum, off);
    ss  += __shfl_xor(ss, off);
  }
  __shared__ float red[2][4];
  int wave = t >> 6, l = t & 63;
  if (l == 0) { red[0][wave] = sum; red[1][wave] = ss; }
  __syncthreads();
  sum = red[0][0] + red[0][1] + red[0][2] + red[0][3];
  ss  = red[1][0] + red[1][1] + red[1][2] + red[1][3];
  float mu = sum * (1.0f / DIM_);
  float var = ss * (1.0f / DIM_) - mu * mu;
  float rs = rsqrtf(var + 1e-5f);
  f32x4 g = ((const f32x4*)gamma)[t];
  f32x4 bb = ((const f32x4*)beta)[t];
  us4 o;
#pragma unroll
  for (int j = 0; j < 4; j++) o[j] = f2b((v[j] - mu) * rs * g[j] + bb[j]);
  int c0 = t * 4;
  if (c0 >= 512) {
    *(us4*)(xs + (size_t)row * DIM_ + c0) = o;
  } else {
    if (row + 1 < NTOK) *(us4*)(xs + (size_t)(row + 1) * DIM_ + c0) = o;
    if (row == 0) { us4 z = {0, 0, 0, 0}; *(us4*)(xs + c0) = z; }
  }
}

// ---------------------------------------------------------------------------
// f32 (R,C) -> bf16 (C,R) transpose; R,C multiples of 32. block (32,8)
// ---------------------------------------------------------------------------
__global__ __launch_bounds__(256) void transpose_f32_bf16(const float* __restrict__ in,
                                                          unsigned short* __restrict__ out,
                                                          int R, int C) {
  __shared__ unsigned short tile[32][33];
  int bx = blockIdx.x * 32, by = blockIdx.y * 32;
  int tx = threadIdx.x, ty = threadIdx.y;
#pragma unroll
  for (int i = 0; i < 32; i += 8) tile[ty + i][tx] = f2b(in[(size_t)(by + ty + i) * C + bx + tx]);
  __syncthreads();
#pragma unroll
  for (int i = 0; i < 32; i += 8) out[(size_t)(bx + ty + i) * R + by + tx] = tile[tx][ty + i];
}

// ---------------------------------------------------------------------------
// One BK=64 K-tile: issue A(kt+1)->LDS + B(kt+1)->regs, 4 phases x 16 MFMA
// using B from registers (bu), then vmcnt(0) + single barrier.
// ---------------------------------------------------------------------------
__device__ __forceinline__ void gemm_tile_body(int kt, int nk, char* lds,
                                               const unsigned short* gA,
                                               const unsigned short* gB0,
                                               const unsigned short* gB1,
                                               const unsigned short* gB2,
                                               const unsigned short* gB3,
                                               int K, int t16,
                                               f32x4 (&acc)[8][4],
                                               s8 (&bu)[8], s8 (&bn)[8],
                                               int wm, int ll, int lg) {
  const char* sa = lds + (kt & 1) * 32768;
  __builtin_amdgcn_sched_barrier(0);
  if (kt + 1 < nk) {
    // A(kt+1) -> other LDS slot (DMA, HBM-latency: issue first)
    char* dA = lds + ((kt + 1) & 1) * 32768;
    const unsigned short* nA = gA + (kt + 1) * 64;
#pragma unroll
    for (int j = 0; j < 4; j++) gload_lds16(nA + (size_t)(j * 64) * K, dA + j * 8192 + t16);
    // B(kt+1) -> registers (per-lane gather from L2-resident panel)
    int c = (kt + 1) * 64;
    bn[0] = *(const s8*)(gB0 + c);  bn[4] = *(const s8*)(gB0 + c + 32);
    bn[1] = *(const s8*)(gB1 + c);  bn[5] = *(const s8*)(gB1 + c + 32);
    bn[2] = *(const s8*)(gB2 + c);  bn[6] = *(const s8*)(gB2 + c + 32);
    bn[3] = *(const s8*)(gB3 + c);  bn[7] = *(const s8*)(gB3 + c + 32);
  }
  __builtin_amdgcn_sched_barrier(0);
#pragma unroll
  for (int p = 0; p < 4; ++p) {
    const int qm = p & 1, kk = p >> 1;
    s8 af[4];
#pragma unroll
    for (int m = 0; m < 4; m++) {
      int r = wm * 128 + qm * 64 + m * 16 + ll;
      af[m] = *(const s8*)(sa + r * 128 + (((kk * 4 + lg) ^ (r & 7)) << 4));
    }
    __builtin_amdgcn_s_setprio(1);
#pragma unroll
    for (int m = 0; m < 4; m++)
#pragma unroll
      for (int n = 0; n < 4; n++)
        acc[qm * 4 + m][n] =
            __builtin_amdgcn_mfma_f32_16x16x32_bf16(af[m], bu[kk * 4 + n], acc[qm * 4 + m][n], 0, 0, 0);
    __builtin_amdgcn_s_setprio(0);
  }
  if (kt + 1 < nk) asm volatile("s_waitcnt vmcnt(0)" ::: "memory");
  __builtin_amdgcn_sched_barrier(0);
  __builtin_amdgcn_s_barrier();
  __builtin_amdgcn_sched_barrier(0);
}

// ---------------------------------------------------------------------------
// NT GEMM p13 (B-in-registers): C[M,N] = A[M,K] @ Bt[N,K]^T.
// BM=BN=256, BK=64, 512 thr (8 waves 2Mx4N, wave tile 128x64).
// A: global_load_lds, 2-slot dbuf (64 KiB). B: per-wave register double
// buffer loaded directly from the L2/L3-resident Bt panel — removes B's
// LDS reads AND stage-writes (the LDS pipe was the measured 26-34%
// MfmaUtil ceiling: 256KB LDS traffic/block-tile vs 614cyc MFMA).
// One barrier + vmcnt(0) per tile.
// NOTE: __launch_bounds__(512,2) REQUIRED — acc(128)+B regs(64) unified;
// min-4 bound would spill (round 7: 8x slower).
// MODE 0: RoPE epilogue -> qh/kh (lane-quad transpose) + vt (lane-pair shfl,
// direct-transposed us4). MODE 1: f32 C + bias.
// ---------------------------------------------------------------------------
template <int MODE>
__global__ __launch_bounds__(512, 2) void gemm_p13(const unsigned short* __restrict__ A,
                                                   const unsigned short* __restrict__ Bt,
                                                   void* __restrict__ Cv,
                                                   const float* __restrict__ bias,
                                                   const float* __restrict__ sinp,
                                                   const float* __restrict__ cosp,
                                                   unsigned short* __restrict__ qh,
                                                   unsigned short* __restrict__ kh,
                                                   unsigned short* __restrict__ vt,
                                                   int M, int N, int K) {
  __shared__ __align__(16) char lds[65536];   // A slots 0/1 @ s*32768
  int t = threadIdx.x;
  int l = t & 63, lg = l >> 4, ll = l & 15;
  int wave = t >> 6;
  int wm = wave >> 2, wn = wave & 3;

  // XCD-bijective flat block swizzle (nwg % 8 == 0 for all our grids)
  int nbx = gridDim.x;
  int nwg = nbx * gridDim.y;
  int flat = blockIdx.y * nbx + blockIdx.x;
  int swz = (flat & 7) * (nwg >> 3) + (flat >> 3);
  int m0 = (swz / nbx) * 256, n0 = (swz % nbx) * 256;

  const f32x4 fz = {0.f, 0.f, 0.f, 0.f};
  f32x4 acc[8][4];
#pragma unroll
  for (int m = 0; m < 8; m++)
#pragma unroll
    for (int n = 0; n < 4; n++) acc[m][n] = fz;

  // A staging: issue j covers rows j*64 + (t>>3), unit (t&7)^(row&7); 8KB/issue
  int srow = t >> 3;                           // 0..63
  int sunit = (t & 7) ^ (srow & 7);            // pre-swizzled source 16B-unit
  const unsigned short* gA = A + (size_t)(m0 + srow) * K + sunit * 8;
  int t16 = t * 16;
  int nk = K >> 6;

  // B register-load bases: row (n0 + wn*64 + n*16 + ll), col lg*8
  const unsigned short* gB0 = Bt + (size_t)(n0 + wn * 64 + ll) * K + lg * 8;
  const unsigned short* gB1 = gB0 + (size_t)16 * K;
  const unsigned short* gB2 = gB0 + (size_t)32 * K;
  const unsigned short* gB3 = gB0 + (size_t)48 * K;

  s8 b0[8], b1[8];

  // prologue: A(0)->slot0 (DMA), B(0)->b0 (regs)
#pragma unroll
  for (int j = 0; j < 4; j++) gload_lds16(gA + (size_t)(j * 64) * K, lds + j * 8192 + t16);
  b0[0] = *(const s8*)(gB0);  b0[4] = *(const s8*)(gB0 + 32);
  b0[1] = *(const s8*)(gB1);  b0[5] = *(const s8*)(gB1 + 32);
  b0[2] = *(const s8*)(gB2);  b0[6] = *(const s8*)(gB2 + 32);
  b0[3] = *(const s8*)(gB3);  b0[7] = *(const s8*)(gB3 + 32);
  asm volatile("s_waitcnt vmcnt(0)" ::: "memory");
  __builtin_amdgcn_sched_barrier(0);
  __builtin_amdgcn_s_barrier();
  __builtin_amdgcn_sched_barrier(0);

  for (int kt2 = 0; kt2 < nk; kt2 += 2) {
    gemm_tile_body(kt2, nk, lds, gA, gB0, gB1, gB2, gB3, K, t16, acc, b0, b1, wm, ll, lg);
    gemm_tile_body(kt2 + 1, nk, lds, gA, gB0, gB1, gB2, gB3, K, t16, acc, b1, b0, wm, ll, lg);
  }

  if (MODE == 0) {
    int third = n0 >> 9;  // block-uniform: 0=q, 1=k, 2=v
    if (third == 2) {
      // v: pre-transpose each lane holds rows lg*4..+3 (tokens) of col d.
      // RoPE partner (d^1) is lane ll^1 -> one shfl_xor per element.
      bool odd = (ll & 1) != 0;
#pragma unroll
      for (int m = 0; m < 8; m++) {
        int row0 = m0 + wm * 128 + m * 16 + lg * 4;
#pragma unroll
        for (int n = 0; n < 4; n++) {
          int cit = (n0 - 1024) + wn * 64 + n * 16 + ll;
          int head = cit >> 6, d = cit & 63;
          us4 st;
#pragma unroll
          for (int r = 0; r < 4; r++) {
            float v = acc[m][n][r];
            float p = __shfl_xor(v, 1);
            float sn = sinp[(size_t)(row0 + r) * 64 + d];
            float cs = cosp[(size_t)(row0 + r) * 64 + d];
            st[r] = f2b(odd ? (v * cs + p * sn) : (v * cs - p * sn));
          }
          *(us4*)(vt + ((size_t)head * 64 + d) * NTOK + row0) = st;
        }
      }
    } else {
      // q/k: 4x4 lane-quad transpose -> lane holds (row = lg*4+b, cols q*4..+3);
      // RoPE pairs lane-local; coalesced us4 stores.
      int b = ll & 3, q = ll >> 2;
      bool bo1 = (b & 1) != 0, bo2 = (b & 2) != 0;
#pragma unroll
      for (int m = 0; m < 8; m++) {
        int row = m0 + wm * 128 + m * 16 + lg * 4 + b;  // token
#pragma unroll
        for (int n = 0; n < 4; n++) {
          float v0 = acc[m][n][0], v1 = acc[m][n][1], v2 = acc[m][n][2], v3 = acc[m][n][3];
          float x0 = __shfl_xor(v1, 1);
          float x1 = __shfl_xor(v0, 1);
          float x2 = __shfl_xor(v3, 1);
          float x3 = __shfl_xor(v2, 1);
          float u0 = bo1 ? x0 : v0;
          float u1 = bo1 ? v1 : x1;
          float u2 = bo1 ? x2 : v2;
          float u3 = bo1 ? v3 : x3;
          float y0 = __shfl_xor(u2, 2);
          float y1 = __shfl_xor(u3, 2);
          float y2 = __shfl_xor(u0, 2);
          float y3 = __shfl_xor(u1, 2);
          float w0 = bo2 ? y0 : u0;
          float w1 = bo2 ? y1 : u1;
          float w2 = bo2 ? u2 : y2;
          float w3 = bo2 ? u3 : y3;
          int cb = n0 + wn * 64 + n * 16 + q * 4;
          int cit = cb & 511;
          int head = cit >> 6, d0 = cit & 63;
          f32x4 s4 = *(const f32x4*)(sinp + (size_t)row * 64 + d0);
          f32x4 c4 = *(const f32x4*)(cosp + (size_t)row * 64 + d0);
          us4 st;
          st[0] = f2b(w0 * c4[0] - w1 * s4[0]);
          st[1] = f2b(w1 * c4[1] + w0 * s4[1]);
          st[2] = f2b(w2 * c4[2] - w3 * s4[2]);
          st[3] = f2b(w3 * c4[3] + w2 * s4[3]);
          if (third == 0) *(us4*)(qh + ((size_t)head * NTOK + row) * 64 + d0) = st;
          else            *(us4*)(kh + ((size_t)head * NTOK + row) * 64 + d0) = st;
        }
      }
    }
  } else {
#pragma unroll
    for (int n = 0; n < 4; n++) {
      int col = n0 + wn * 64 + n * 16 + ll;
      float bs = bias ? bias[col] : 0.0f;
#pragma unroll
      for (int m = 0; m < 8; m++) {
#pragma unroll
        for (int r = 0; r < 4; r++) {
          int row = m0 + wm * 128 + m * 16 + lg * 4 + r;
          ((float*)Cv)[(size_t)row * N + col] = acc[m][n][r] + bs;
        }
      }
    }
  }
}

// ---------------------------------------------------------------------------
// Windowed lookback attention, v3: 32x32 MFMA, swapped operands.
// block = (half, window, head), 4 waves x 32 q-rows. 8 chunks of 64 keys.
// ---------------------------------------------------------------------------
__global__ __launch_bounds__(256, 4) void attn_kernel(const unsigned short* __restrict__ qh,
                                                      const unsigned short* __restrict__ kh,
                                                      const unsigned short* __restrict__ vt,
                                                      unsigned short* __restrict__ ao) {
  __shared__ char kbuf[2][8192];   // 64 keys x 128B, unit-swizzled by (row&7)
  __shared__ char vbuf[8192];      // 64 d x 128B (64 keys), unit-swizzled by (d&7)
  int half = blockIdx.x, w = blockIdx.y, h = blockIdx.z;
  int t = threadIdx.x;
  int wave = t >> 6, l = t & 63;
  int l31 = l & 31, hi = l >> 5;
  const unsigned short* qb = qh + (size_t)h * NTOK * 64;
  const unsigned short* kb = kh + (size_t)h * NTOK * 64;
  const unsigned short* vb = vt + (size_t)h * 64 * NTOK;

  int qw = half * 128 + wave * 32 + l31;   // q within window
  int qn = w * 256 + qw;                   // global token
  s8 qf[4];
#pragma unroll
  for (int dht = 0; dht < 4; dht++)
    qf[dht] = *(const s8*)(qb + (size_t)qn * 64 + dht * 16 + hi * 8);

  f32x16 o0 = {}, o1 = {};
  float dsum = (w == 0) ? 128.f : 0.f;     // 256 zero-keys -> exp(0)=1, split across hi halves
  int n0 = w * 256 - 256;
  int c0 = (w == 0) ? 4 : 0;

  int srow = wave * 16 + (l >> 3);
  int sunit = l & 7;

  // prologue: stage K(c0)
  {
    const unsigned short* g = kb + (size_t)(n0 + c0 * 64 + srow) * 64 + ((sunit ^ (srow & 7)) * 8);
    gload_lds16(g, kbuf[c0 & 1] + wave * 2048);
    gload_lds16(g + 8 * 64, kbuf[c0 & 1] + wave * 2048 + 1024);
  }
  __syncthreads();

  for (int c = c0; c < 8; ++c) {
    int cb = n0 + c * 64;
    // stage V(c)
    {
      int d = srow;
      const unsigned short* g = vb + (size_t)d * NTOK + cb + ((sunit ^ (d & 7)) * 8);
      gload_lds16(g, vbuf + wave * 2048);
      gload_lds16(g + (size_t)8 * NTOK, vbuf + wave * 2048 + 1024);
    }
    // stage K(c+1)
    if (c < 7) {
      const unsigned short* g = kb + (size_t)(cb + 64 + srow) * 64 + ((sunit ^ (srow & 7)) * 8);
      gload_lds16(g, kbuf[(c + 1) & 1] + wave * 2048);
      gload_lds16(g + 8 * 64, kbuf[(c + 1) & 1] + wave * 2048 + 1024);
    }

    // QK^T (swapped): S^T tiles, 64 keys x 32 q
    f32x16 s[2] = {{}, {}};
    const char* kl = kbuf[c & 1];
#pragma unroll
    for (int kt = 0; kt < 2; kt++) {
#pragma unroll
      for (int dht = 0; dht < 4; dht++) {
        int row = kt * 32 + l31;
        int unit = (dht * 2 + hi) ^ (row & 7);
        s8 kf = *(const s8*)(kl + row * 128 + unit * 16);
        s[kt] = __builtin_amdgcn_mfma_f32_32x32x16_bf16(kf, qf[dht], s[kt], 0, 0, 0);
      }
    }

    // masked exp (no max-sub) + denominator + pack to bf16 pairs
    unsigned P0[2][4], P1[2][4];
#pragma unroll
    for (int kt = 0; kt < 2; kt++) {
#pragma unroll
      for (int r = 0; r < 16; r++) {
        int j = c * 64 + kt * 32 + (r & 3) + 8 * (r >> 2) + hi * 4;
        float e = (j <= qw + 256) ? __expf(s[kt][r] * 0.125f) : 0.f;
        s[kt][r] = e;
        dsum += e;
      }
#pragma unroll
      for (int j2 = 0; j2 < 4; j2++) {
        P0[kt][j2] = pk2(s[kt][j2 * 4 + 0], s[kt][j2 * 4 + 1]);
        P1[kt][j2] = pk2(s[kt][j2 * 4 + 2], s[kt][j2 * 4 + 3]);
      }
    }

    __syncthreads();   // V(c) staged (drains K(c+1) too)

    // PV (swapped): O^T += V^T(chunk) . P^T(chunk)
#pragma unroll
    for (int tt = 0; tt < 4; tt++) {
      int kt = tt >> 1, ss = tt & 1;
      unsigned a = P0[kt][2 * ss], b = P1[kt][2 * ss];
      unsigned cx = P0[kt][2 * ss + 1], dx = P1[kt][2 * ss + 1];
      asm volatile("v_permlane32_swap_b32 %0, %1" : "+v"(a), "+v"(cx));
      asm volatile("v_permlane32_swap_b32 %0, %1" : "+v"(b), "+v"(dx));
      s8 pf = mk_s8(a, b, cx, dx);
      {
        int row = l31;
        int unit = (tt * 2 + hi) ^ (row & 7);
        s8 vf = *(const s8*)(vbuf + row * 128 + unit * 16);
        o0 = __builtin_amdgcn_mfma_f32_32x32x16_bf16(vf, pf, o0, 0, 0, 0);
      }
      {
        int row = 32 + l31;
        int unit = (tt * 2 + hi) ^ (row & 7);
        s8 vf = *(const s8*)(vbuf + row * 128 + unit * 16);
        o1 = __builtin_amdgcn_mfma_f32_32x32x16_bf16(vf, pf, o1, 0, 0, 0);
      }
    }
    __syncthreads();   // LDS consumed; next iter may overwrite
  }

  dsum += __shfl_xor(dsum, 32);
  float inv = 1.f / dsum;

  unsigned short* orow = ao + (size_t)qn * INNER_ + h * 64;
#pragma unroll
  for (int g = 0; g < 4; g++) {
    us4 st0, st1;
#pragma unroll
    for (int rr = 0; rr < 4; rr++) {
      st0[rr] = f2b(o0[g * 4 + rr] * inv);
      st1[rr] = f2b(o1[g * 4 + rr] * inv);
    }
    *(us4*)(orow + g * 8 + hi * 4) = st0;
    *(us4*)(orow + 32 + g * 8 + hi * 4) = st1;
  }
}

// ---------------------------------------------------------------------------
extern "C" void kernel_launch(void* const* d_in, const int* in_sizes, int n_in,
                              void* d_out, int out_size, void* d_ws, size_t ws_size,
                              hipStream_t stream) {
  const float* x     = (const float*)d_in[0];
  const float* sin_  = (const float*)d_in[1];
  const float* cos_  = (const float*)d_in[2];
  const float* gamma = (const float*)d_in[3];
  const float* beta  = (const float*)d_in[4];
  const float* w_qkv = (const float*)d_in[5];
  const float* w_out = (const float*)d_in[6];
  const float* b_out = (const float*)d_in[7];

  // ws layout (bytes). total needed = 171,966,464
  char* ws = (char*)d_ws;
  const size_t OFF_WQT = 0;                    // 1536*1024*2 = 3,145,728
  const size_t OFF_WOT = 3145728;              // 1024*512*2  = 1,048,576
  const size_t OFF_XS  = 4194304;              // 32768*1024*2 = 67,108,864 (xs; later ao)
  const size_t OFF_QH  = 71303168;             // 8*32768*64*2 = 33,554,432
  const size_t OFF_KH  = 104857600;            // 33,554,432
  const size_t OFF_VT  = 138412032;            // 8*64*32768*2 = 33,554,432
  const size_t NEEDED  = 171966464;
  if (ws_size < NEEDED) return;  // fail loudly (output stays poisoned)

  unsigned short* wqT = (unsigned short*)(ws + OFF_WQT);
  unsigned short* woT = (unsigned short*)(ws + OFF_WOT);
  unsigned short* xs  = (unsigned short*)(ws + OFF_XS);
  unsigned short* qh  = (unsigned short*)(ws + OFF_QH);
  unsigned short* kh  = (unsigned short*)(ws + OFF_KH);
  unsigned short* vt  = (unsigned short*)(ws + OFF_VT);
  unsigned short* ao  = xs;   // xs dead after gemm1; attn writes ao here

  transpose_f32_bf16<<<dim3(1536 / 32, 1024 / 32), dim3(32, 8), 0, stream>>>(w_qkv, wqT, 1024, 1536);
  transpose_f32_bf16<<<dim3(1024 / 32, 512 / 32), dim3(32, 8), 0, stream>>>(w_out, woT, 512, 1024);
  ln_shift<<<NTOK, 256, 0, stream>>>(x, gamma, beta, xs);
  gemm_p13<0><<<dim3(1536 / 256, NTOK / 256), 512, 0, stream>>>(
      xs, wqT, nullptr, nullptr, sin_, cos_, qh, kh, vt, NTOK, 1536, 1024);
  attn_kernel<<<dim3(2, NWIN_, HEADS_), 256, 0, stream>>>(qh, kh, vt, ao);
  gemm_p13<1><<<dim3(1024 / 256, NTOK / 256), 512, 0, stream>>>(
      ao, woT, (void*)d_out, b_out, nullptr, nullptr, nullptr, nullptr, nullptr, NTOK, 1024, 512);
}

// Round 15
// 486.466 us; speedup vs baseline: 1.0155x; 1.0025x over previous
//
#include <hip/hip_runtime.h>

typedef __attribute__((ext_vector_type(4))) unsigned short us4;
typedef __attribute__((ext_vector_type(8))) unsigned short us8;
typedef __attribute__((ext_vector_type(8))) short s8;      // MFMA A/B fragment (8 bf16)
typedef __attribute__((ext_vector_type(4))) float f32x4;   // 16x16 MFMA acc / float4
typedef __attribute__((ext_vector_type(16))) float f32x16; // 32x32 MFMA acc

#define NTOK 32768
#define DIM_ 1024
#define HEADS_ 8
#define DH_ 64
#define WS_ 256
#define NWIN_ 128
#define INNER_ 512

__device__ __forceinline__ float b2f(unsigned short u) {
  union { unsigned u; float f; } x; x.u = ((unsigned)u) << 16; return x.f;
}
__device__ __forceinline__ unsigned short f2b(float f) {
  union { float f; unsigned u; } x; x.f = f;
  unsigned r = x.u + 0x7FFFu + ((x.u >> 16) & 1u);  // RNE
  return (unsigned short)(r >> 16);
}
__device__ __forceinline__ unsigned pk2(float a, float b) {
  return (unsigned)f2b(a) | ((unsigned)f2b(b) << 16);
}
__device__ __forceinline__ s8 mk_s8(unsigned w0, unsigned w1, unsigned w2, unsigned w3) {
  union { unsigned u[4]; s8 v; } x;
  x.u[0] = w0; x.u[1] = w1; x.u[2] = w2; x.u[3] = w3;
  return x.v;
}

// global -> LDS direct DMA, 16B per lane. LDS dest = wave-uniform base + lane*16.
__device__ __forceinline__ void gload_lds16(const unsigned short* g, void* l) {
  __builtin_amdgcn_global_load_lds((const __attribute__((address_space(1))) void*)g,
                                   (__attribute__((address_space(3))) void*)l, 16, 0, 0);
}

// ---------------------------------------------------------------------------
// LayerNorm (f32 in) + half-row shift -> bf16 xs.
// ---------------------------------------------------------------------------
__global__ __launch_bounds__(256) void ln_shift(const float* __restrict__ x,
                                                const float* __restrict__ gamma,
                                                const float* __restrict__ beta,
                                                unsigned short* __restrict__ xs) {
  int row = blockIdx.x;
  int t = threadIdx.x;
  f32x4 v = ((const f32x4*)(x + (size_t)row * DIM_))[t];
  float sum = 0.f, ss = 0.f;
#pragma unroll
  for (int j = 0; j < 4; j++) { sum += v[j]; ss += v[j] * v[j]; }
#pragma unroll
  for (int off = 32; off >= 1; off >>= 1) {
    sum += __shfl_xor(sum, off);
    ss  += __shfl_xor(ss, off);
  }
  __shared__ float red[2][4];
  int wave = t >> 6, l = t & 63;
  if (l == 0) { red[0][wave] = sum; red[1][wave] = ss; }
  __syncthreads();
  sum = red[0][0] + red[0][1] + red[0][2] + red[0][3];
  ss  = red[1][0] + red[1][1] + red[1][2] + red[1][3];
  float mu = sum * (1.0f / DIM_);
  float var = ss * (1.0f / DIM_) - mu * mu;
  float rs = rsqrtf(var + 1e-5f);
  f32x4 g = ((const f32x4*)gamma)[t];
  f32x4 bb = ((const f32x4*)beta)[t];
  us4 o;
#pragma unroll
  for (int j = 0; j < 4; j++) o[j] = f2b((v[j] - mu) * rs * g[j] + bb[j]);
  int c0 = t * 4;
  if (c0 >= 512) {
    *(us4*)(xs + (size_t)row * DIM_ + c0) = o;
  } else {
    if (row + 1 < NTOK) *(us4*)(xs + (size_t)(row + 1) * DIM_ + c0) = o;
    if (row == 0) { us4 z = {0, 0, 0, 0}; *(us4*)(xs + c0) = z; }
  }
}

// ---------------------------------------------------------------------------
// Pack weight w (K x N, f32 row-major) into MFMA-fragment order:
// Bpk[ntile][kt32][lane][8] bf16, lane = lg*16+ll, element (n,k) with
// n = ntile*16+ll, k = kt32*32+lg*8+j. A wave's B-frag = contiguous 1KB.
// one thread = one 16B chunk. grid = N*K/8/256 blocks.
// ---------------------------------------------------------------------------
__global__ __launch_bounds__(256) void pack_w(const float* __restrict__ w,
                                              unsigned short* __restrict__ out,
                                              int K, int N) {
  int flat = blockIdx.x * 256 + threadIdx.x;
  int lane = flat & 63;
  int nk32 = K >> 5;
  int grp = flat >> 6;
  int kt32 = grp % nk32;
  int ntile = grp / nk32;
  int ll = lane & 15, lg = lane >> 4;
  int n = ntile * 16 + ll;
  int k0 = kt32 * 32 + lg * 8;
  us8 o;
#pragma unroll
  for (int j = 0; j < 8; j++) o[j] = f2b(w[(size_t)(k0 + j) * N + n]);
  *(us8*)(out + (size_t)flat * 8) = o;
}

// ---------------------------------------------------------------------------
// One BK=64 K-tile: issue A(kt+1)->LDS (DMA) + B(kt+1)->regs (coalesced
// packed-fragment loads), 4 phases x 16 MFMA using bu, vmcnt(0)+barrier.
// ---------------------------------------------------------------------------
__device__ __forceinline__ void tile_body15(int kt, int nk, char* lds,
                                            const unsigned short* gA,
                                            const unsigned short* Bw, int nk32,
                                            int K, int t16,
                                            f32x4 (&acc)[8][4],
                                            s8 (&bu)[8], s8 (&bn)[8],
                                            int wm, int ll, int lg) {
  const char* sa = lds + (kt & 1) * 32768;
  __builtin_amdgcn_sched_barrier(0);
  if (kt + 1 < nk) {
    char* dA = lds + ((kt + 1) & 1) * 32768;
    const unsigned short* nA = gA + (kt + 1) * 64;
#pragma unroll
    for (int j = 0; j < 4; j++) gload_lds16(nA + (size_t)(j * 64) * K, dA + j * 8192 + t16);
    int c = (kt + 1) * 2;
#pragma unroll
    for (int n = 0; n < 4; n++) {
      bn[n]     = *(const s8*)(Bw + ((size_t)n * nk32 + c) * 512);
      bn[4 + n] = *(const s8*)(Bw + ((size_t)n * nk32 + c + 1) * 512);
    }
  }
  __builtin_amdgcn_sched_barrier(0);
#pragma unroll
  for (int p = 0; p < 4; ++p) {
    const int qm = p & 1, kk = p >> 1;
    s8 af[4];
#pragma unroll
    for (int m = 0; m < 4; m++) {
      int r = wm * 128 + qm * 64 + m * 16 + ll;
      af[m] = *(const s8*)(sa + r * 128 + (((kk * 4 + lg) ^ (r & 7)) << 4));
    }
    __builtin_amdgcn_s_setprio(1);
#pragma unroll
    for (int m = 0; m < 4; m++)
#pragma unroll
      for (int n = 0; n < 4; n++)
        acc[qm * 4 + m][n] =
            __builtin_amdgcn_mfma_f32_16x16x32_bf16(af[m], bu[kk * 4 + n], acc[qm * 4 + m][n], 0, 0, 0);
    __builtin_amdgcn_s_setprio(0);
  }
  if (kt + 1 < nk) asm volatile("s_waitcnt vmcnt(0)" ::: "memory");
  __builtin_amdgcn_sched_barrier(0);
  __builtin_amdgcn_s_barrier();
  __builtin_amdgcn_sched_barrier(0);
}

// ---------------------------------------------------------------------------
// NT GEMM p15 (B as packed-fragment register loads):
// C[M,N] = A[M,K] @ B^T. BM=BN=256, BK=64, 512 thr (8 waves 2Mx4N).
// A: global_load_lds 2-slot dbuf (64 KiB LDS total). B: coalesced 1KB
// fragment loads from L2-resident packed panel straight to registers —
// removes B's LDS reads AND stage-writes (LDS pipe was the measured
// ~30% MfmaUtil ceiling: 256KB -> 160KB LDS traffic per block-tile).
// NOTE: __launch_bounds__(512,2) REQUIRED — acc(128)+B(64) unified regs;
// min-4 bound spills the accumulator (round 7: 8x slower).
// MODE 0: RoPE epilogue -> qh/kh (lane-quad transpose) + vt (lane-pair shfl,
// direct-transposed us4). MODE 1: f32 C + bias.
// ---------------------------------------------------------------------------
template <int MODE>
__global__ __launch_bounds__(512, 2) void gemm_p15(const unsigned short* __restrict__ A,
                                                   const unsigned short* __restrict__ Bpk,
                                                   void* __restrict__ Cv,
                                                   const float* __restrict__ bias,
                                                   const float* __restrict__ sinp,
                                                   const float* __restrict__ cosp,
                                                   unsigned short* __restrict__ qh,
                                                   unsigned short* __restrict__ kh,
                                                   unsigned short* __restrict__ vt,
                                                   int M, int N, int K) {
  __shared__ __align__(16) char lds[65536];   // A slots 0/1 @ s*32768
  int t = threadIdx.x;
  int l = t & 63, lg = l >> 4, ll = l & 15;
  int wave = t >> 6;
  int wm = wave >> 2, wn = wave & 3;

  // XCD-bijective flat block swizzle (nwg % 8 == 0 for all our grids)
  int nbx = gridDim.x;
  int nwg = nbx * gridDim.y;
  int flat = blockIdx.y * nbx + blockIdx.x;
  int swz = (flat & 7) * (nwg >> 3) + (flat >> 3);
  int m0 = (swz / nbx) * 256, n0 = (swz % nbx) * 256;

  const f32x4 fz = {0.f, 0.f, 0.f, 0.f};
  f32x4 acc[8][4];
#pragma unroll
  for (int m = 0; m < 8; m++)
#pragma unroll
    for (int n = 0; n < 4; n++) acc[m][n] = fz;

  // A staging: issue j covers rows j*64 + (t>>3), unit (t&7)^(row&7); 8KB/issue
  int srow = t >> 3;                           // 0..63
  int sunit = (t & 7) ^ (srow & 7);            // pre-swizzled source 16B-unit
  const unsigned short* gA = A + (size_t)(m0 + srow) * K + sunit * 8;
  int t16 = t * 16;
  int nk = K >> 6;
  int nk32 = K >> 5;

  // B packed base for this wave: ntile base = n0/16 + wn*4; lane offset l*8
  const unsigned short* Bw = Bpk + ((size_t)(n0 >> 4) + wn * 4) * nk32 * 512 + (size_t)l * 8;

  s8 b0[8], b1[8];

  // prologue: A(0)->slot0 (DMA), B(0)->b0 (coalesced frag loads)
#pragma unroll
  for (int j = 0; j < 4; j++) gload_lds16(gA + (size_t)(j * 64) * K, lds + j * 8192 + t16);
#pragma unroll
  for (int n = 0; n < 4; n++) {
    b0[n]     = *(const s8*)(Bw + ((size_t)n * nk32) * 512);
    b0[4 + n] = *(const s8*)(Bw + ((size_t)n * nk32 + 1) * 512);
  }
  asm volatile("s_waitcnt vmcnt(0)" ::: "memory");
  __builtin_amdgcn_sched_barrier(0);
  __builtin_amdgcn_s_barrier();
  __builtin_amdgcn_sched_barrier(0);

  for (int kt2 = 0; kt2 < nk; kt2 += 2) {
    tile_body15(kt2, nk, lds, gA, Bw, nk32, K, t16, acc, b0, b1, wm, ll, lg);
    tile_body15(kt2 + 1, nk, lds, gA, Bw, nk32, K, t16, acc, b1, b0, wm, ll, lg);
  }

  if (MODE == 0) {
    int third = n0 >> 9;  // block-uniform: 0=q, 1=k, 2=v
    if (third == 2) {
      // v: pre-transpose each lane holds rows lg*4..+3 (tokens) of col d.
      // RoPE partner (d^1) is lane ll^1 -> one shfl_xor per element.
      bool odd = (ll & 1) != 0;
#pragma unroll
      for (int m = 0; m < 8; m++) {
        int row0 = m0 + wm * 128 + m * 16 + lg * 4;
#pragma unroll
        for (int n = 0; n < 4; n++) {
          int cit = (n0 - 1024) + wn * 64 + n * 16 + ll;
          int head = cit >> 6, d = cit & 63;
          us4 st;
#pragma unroll
          for (int r = 0; r < 4; r++) {
            float v = acc[m][n][r];
            float p = __shfl_xor(v, 1);
            float sn = sinp[(size_t)(row0 + r) * 64 + d];
            float cs = cosp[(size_t)(row0 + r) * 64 + d];
            st[r] = f2b(odd ? (v * cs + p * sn) : (v * cs - p * sn));
          }
          *(us4*)(vt + ((size_t)head * 64 + d) * NTOK + row0) = st;
        }
      }
    } else {
      // q/k: 4x4 lane-quad transpose -> lane holds (row = lg*4+b, cols q*4..+3);
      // RoPE pairs lane-local; coalesced us4 stores.
      int b = ll & 3, q = ll >> 2;
      bool bo1 = (b & 1) != 0, bo2 = (b & 2) != 0;
#pragma unroll
      for (int m = 0; m < 8; m++) {
        int row = m0 + wm * 128 + m * 16 + lg * 4 + b;  // token
#pragma unroll
        for (int n = 0; n < 4; n++) {
          float v0 = acc[m][n][0], v1 = acc[m][n][1], v2 = acc[m][n][2], v3 = acc[m][n][3];
          float x0 = __shfl_xor(v1, 1);
          float x1 = __shfl_xor(v0, 1);
          float x2 = __shfl_xor(v3, 1);
          float x3 = __shfl_xor(v2, 1);
          float u0 = bo1 ? x0 : v0;
          float u1 = bo1 ? v1 : x1;
          float u2 = bo1 ? x2 : v2;
          float u3 = bo1 ? v3 : x3;
          float y0 = __shfl_xor(u2, 2);
          float y1 = __shfl_xor(u3, 2);
          float y2 = __shfl_xor(u0, 2);
          float y3 = __shfl_xor(u1, 2);
          float w0 = bo2 ? y0 : u0;
          float w1 = bo2 ? y1 : u1;
          float w2 = bo2 ? u2 : y2;
          float w3 = bo2 ? u3 : y3;
          int cb = n0 + wn * 64 + n * 16 + q * 4;
          int cit = cb & 511;
          int head = cit >> 6, d0 = cit & 63;
          f32x4 s4 = *(const f32x4*)(sinp + (size_t)row * 64 + d0);
          f32x4 c4 = *(const f32x4*)(cosp + (size_t)row * 64 + d0);
          us4 st;
          st[0] = f2b(w0 * c4[0] - w1 * s4[0]);
          st[1] = f2b(w1 * c4[1] + w0 * s4[1]);
          st[2] = f2b(w2 * c4[2] - w3 * s4[2]);
          st[3] = f2b(w3 * c4[3] + w2 * s4[3]);
          if (third == 0) *(us4*)(qh + ((size_t)head * NTOK + row) * 64 + d0) = st;
          else            *(us4*)(kh + ((size_t)head * NTOK + row) * 64 + d0) = st;
        }
      }
    }
  } else {
#pragma unroll
    for (int n = 0; n < 4; n++) {
      int col = n0 + wn * 64 + n * 16 + ll;
      float bs = bias ? bias[col] : 0.0f;
#pragma unroll
      for (int m = 0; m < 8; m++) {
#pragma unroll
        for (int r = 0; r < 4; r++) {
          int row = m0 + wm * 128 + m * 16 + lg * 4 + r;
          ((float*)Cv)[(size_t)row * N + col] = acc[m][n][r] + bs;
        }
      }
    }
  }
}

// ---------------------------------------------------------------------------
// Windowed lookback attention, v3: 32x32 MFMA, swapped operands.
// block = (half, window, head), 4 waves x 32 q-rows. 8 chunks of 64 keys.
// ---------------------------------------------------------------------------
__global__ __launch_bounds__(256, 4) void attn_kernel(const unsigned short* __restrict__ qh,
                                                      const unsigned short* __restrict__ kh,
                                                      const unsigned short* __restrict__ vt,
                                                      unsigned short* __restrict__ ao) {
  __shared__ char kbuf[2][8192];   // 64 keys x 128B, unit-swizzled by (row&7)
  __shared__ char vbuf[8192];      // 64 d x 128B (64 keys), unit-swizzled by (d&7)
  int half = blockIdx.x, w = blockIdx.y, h = blockIdx.z;
  int t = threadIdx.x;
  int wave = t >> 6, l = t & 63;
  int l31 = l & 31, hi = l >> 5;
  const unsigned short* qb = qh + (size_t)h * NTOK * 64;
  const unsigned short* kb = kh + (size_t)h * NTOK * 64;
  const unsigned short* vb = vt + (size_t)h * 64 * NTOK;

  int qw = half * 128 + wave * 32 + l31;   // q within window
  int qn = w * 256 + qw;                   // global token
  s8 qf[4];
#pragma unroll
  for (int dht = 0; dht < 4; dht++)
    qf[dht] = *(const s8*)(qb + (size_t)qn * 64 + dht * 16 + hi * 8);

  f32x16 o0 = {}, o1 = {};
  float dsum = (w == 0) ? 128.f : 0.f;     // 256 zero-keys -> exp(0)=1, split across hi halves
  int n0 = w * 256 - 256;
  int c0 = (w == 0) ? 4 : 0;

  int srow = wave * 16 + (l >> 3);
  int sunit = l & 7;

  // prologue: stage K(c0)
  {
    const unsigned short* g = kb + (size_t)(n0 + c0 * 64 + srow) * 64 + ((sunit ^ (srow & 7)) * 8);
    gload_lds16(g, kbuf[c0 & 1] + wave * 2048);
    gload_lds16(g + 8 * 64, kbuf[c0 & 1] + wave * 2048 + 1024);
  }
  __syncthreads();

  for (int c = c0; c < 8; ++c) {
    int cb = n0 + c * 64;
    // stage V(c)
    {
      int d = srow;
      const unsigned short* g = vb + (size_t)d * NTOK + cb + ((sunit ^ (d & 7)) * 8);
      gload_lds16(g, vbuf + wave * 2048);
      gload_lds16(g + (size_t)8 * NTOK, vbuf + wave * 2048 + 1024);
    }
    // stage K(c+1)
    if (c < 7) {
      const unsigned short* g = kb + (size_t)(cb + 64 + srow) * 64 + ((sunit ^ (srow & 7)) * 8);
      gload_lds16(g, kbuf[(c + 1) & 1] + wave * 2048);
      gload_lds16(g + 8 * 64, kbuf[(c + 1) & 1] + wave * 2048 + 1024);
    }

    // QK^T (swapped): S^T tiles, 64 keys x 32 q
    f32x16 s[2] = {{}, {}};
    const char* kl = kbuf[c & 1];
#pragma unroll
    for (int kt = 0; kt < 2; kt++) {
#pragma unroll
      for (int dht = 0; dht < 4; dht++) {
        int row = kt * 32 + l31;
        int unit = (dht * 2 + hi) ^ (row & 7);
        s8 kf = *(const s8*)(kl + row * 128 + unit * 16);
        s[kt] = __builtin_amdgcn_mfma_f32_32x32x16_bf16(kf, qf[dht], s[kt], 0, 0, 0);
      }
    }

    // masked exp (no max-sub) + denominator + pack to bf16 pairs
    unsigned P0[2][4], P1[2][4];
#pragma unroll
    for (int kt = 0; kt < 2; kt++) {
#pragma unroll
      for (int r = 0; r < 16; r++) {
        int j = c * 64 + kt * 32 + (r & 3) + 8 * (r >> 2) + hi * 4;
        float e = (j <= qw + 256) ? __expf(s[kt][r] * 0.125f) : 0.f;
        s[kt][r] = e;
        dsum += e;
      }
#pragma unroll
      for (int j2 = 0; j2 < 4; j2++) {
        P0[kt][j2] = pk2(s[kt][j2 * 4 + 0], s[kt][j2 * 4 + 1]);
        P1[kt][j2] = pk2(s[kt][j2 * 4 + 2], s[kt][j2 * 4 + 3]);
      }
    }

    __syncthreads();   // V(c) staged (drains K(c+1) too)

    // PV (swapped): O^T += V^T(chunk) . P^T(chunk)
#pragma unroll
    for (int tt = 0; tt < 4; tt++) {
      int kt = tt >> 1, ss = tt & 1;
      unsigned a = P0[kt][2 * ss], b = P1[kt][2 * ss];
      unsigned cx = P0[kt][2 * ss + 1], dx = P1[kt][2 * ss + 1];
      asm volatile("v_permlane32_swap_b32 %0, %1" : "+v"(a), "+v"(cx));
      asm volatile("v_permlane32_swap_b32 %0, %1" : "+v"(b), "+v"(dx));
      s8 pf = mk_s8(a, b, cx, dx);
      {
        int row = l31;
        int unit = (tt * 2 + hi) ^ (row & 7);
        s8 vf = *(const s8*)(vbuf + row * 128 + unit * 16);
        o0 = __builtin_amdgcn_mfma_f32_32x32x16_bf16(vf, pf, o0, 0, 0, 0);
      }
      {
        int row = 32 + l31;
        int unit = (tt * 2 + hi) ^ (row & 7);
        s8 vf = *(const s8*)(vbuf + row * 128 + unit * 16);
        o1 = __builtin_amdgcn_mfma_f32_32x32x16_bf16(vf, pf, o1, 0, 0, 0);
      }
    }
    __syncthreads();   // LDS consumed; next iter may overwrite
  }

  dsum += __shfl_xor(dsum, 32);
  float inv = 1.f / dsum;

  unsigned short* orow = ao + (size_t)qn * INNER_ + h * 64;
#pragma unroll
  for (int g = 0; g < 4; g++) {
    us4 st0, st1;
#pragma unroll
    for (int rr = 0; rr < 4; rr++) {
      st0[rr] = f2b(o0[g * 4 + rr] * inv);
      st1[rr] = f2b(o1[g * 4 + rr] * inv);
    }
    *(us4*)(orow + g * 8 + hi * 4) = st0;
    *(us4*)(orow + 32 + g * 8 + hi * 4) = st1;
  }
}

// ---------------------------------------------------------------------------
extern "C" void kernel_launch(void* const* d_in, const int* in_sizes, int n_in,
                              void* d_out, int out_size, void* d_ws, size_t ws_size,
                              hipStream_t stream) {
  const float* x     = (const float*)d_in[0];
  const float* sin_  = (const float*)d_in[1];
  const float* cos_  = (const float*)d_in[2];
  const float* gamma = (const float*)d_in[3];
  const float* beta  = (const float*)d_in[4];
  const float* w_qkv = (const float*)d_in[5];
  const float* w_out = (const float*)d_in[6];
  const float* b_out = (const float*)d_in[7];

  // ws layout (bytes). total needed = 171,966,464
  char* ws = (char*)d_ws;
  const size_t OFF_WQP = 0;                    // packed wqkv: 1536*1024*2 = 3,145,728
  const size_t OFF_WOP = 3145728;              // packed wout: 1024*512*2  = 1,048,576
  const size_t OFF_XS  = 4194304;              // 32768*1024*2 = 67,108,864 (xs; later ao)
  const size_t OFF_QH  = 71303168;             // 8*32768*64*2 = 33,554,432
  const size_t OFF_KH  = 104857600;            // 33,554,432
  const size_t OFF_VT  = 138412032;            // 8*64*32768*2 = 33,554,432
  const size_t NEEDED  = 171966464;
  if (ws_size < NEEDED) return;  // fail loudly (output stays poisoned)

  unsigned short* wqP = (unsigned short*)(ws + OFF_WQP);
  unsigned short* woP = (unsigned short*)(ws + OFF_WOP);
  unsigned short* xs  = (unsigned short*)(ws + OFF_XS);
  unsigned short* qh  = (unsigned short*)(ws + OFF_QH);
  unsigned short* kh  = (unsigned short*)(ws + OFF_KH);
  unsigned short* vt  = (unsigned short*)(ws + OFF_VT);
  unsigned short* ao  = xs;   // xs dead after gemm1; attn writes ao here

  pack_w<<<(1536 * 1024 / 8) / 256, 256, 0, stream>>>(w_qkv, wqP, 1024, 1536);
  pack_w<<<(1024 * 512 / 8) / 256, 256, 0, stream>>>(w_out, woP, 512, 1024);
  ln_shift<<<NTOK, 256, 0, stream>>>(x, gamma, beta, xs);
  gemm_p15<0><<<dim3(1536 / 256, NTOK / 256), 512, 0, stream>>>(
      xs, wqP, nullptr, nullptr, sin_, cos_, qh, kh, vt, NTOK, 1536, 1024);
  attn_kernel<<<dim3(2, NWIN_, HEADS_), 256, 0, stream>>>(qh, kh, vt, ao);
  gemm_p15<1><<<dim3(1024 / 256, NTOK / 256), 512, 0, stream>>>(
      ao, woP, (void*)d_out, b_out, nullptr, nullptr, nullptr, nullptr, nullptr, NTOK, 1024, 512);
}

// Round 16
// 314.388 us; speedup vs baseline: 1.5713x; 1.5473x over previous
//
#include <hip/hip_runtime.h>

typedef __attribute__((ext_vector_type(4))) unsigned short us4;
typedef __attribute__((ext_vector_type(8))) unsigned short us8;
typedef __attribute__((ext_vector_type(8))) short s8;      // MFMA A/B fragment (8 bf16)
typedef __attribute__((ext_vector_type(4))) float f32x4;   // 16x16 MFMA acc / float4
typedef __attribute__((ext_vector_type(16))) float f32x16; // 32x32 MFMA acc

#define NTOK 32768
#define DIM_ 1024
#define HEADS_ 8
#define DH_ 64
#define WS_ 256
#define NWIN_ 128
#define INNER_ 512

__device__ __forceinline__ float b2f(unsigned short u) {
  union { unsigned u; float f; } x; x.u = ((unsigned)u) << 16; return x.f;
}
__device__ __forceinline__ unsigned short f2b(float f) {
  union { float f; unsigned u; } x; x.f = f;
  unsigned r = x.u + 0x7FFFu + ((x.u >> 16) & 1u);  // RNE
  return (unsigned short)(r >> 16);
}
__device__ __forceinline__ unsigned pk2(float a, float b) {
  return (unsigned)f2b(a) | ((unsigned)f2b(b) << 16);
}
__device__ __forceinline__ s8 mk_s8(unsigned w0, unsigned w1, unsigned w2, unsigned w3) {
  union { unsigned u[4]; s8 v; } x;
  x.u[0] = w0; x.u[1] = w1; x.u[2] = w2; x.u[3] = w3;
  return x.v;
}

// global -> LDS direct DMA, 16B per lane. LDS dest = wave-uniform base + lane*16.
__device__ __forceinline__ void gload_lds16(const unsigned short* g, void* l) {
  __builtin_amdgcn_global_load_lds((const __attribute__((address_space(1))) void*)g,
                                   (__attribute__((address_space(3))) void*)l, 16, 0, 0);
}

// ---------------------------------------------------------------------------
// LayerNorm (f32 in) + half-row shift -> bf16 xs.
// ---------------------------------------------------------------------------
__global__ __launch_bounds__(256) void ln_shift(const float* __restrict__ x,
                                                const float* __restrict__ gamma,
                                                const float* __restrict__ beta,
                                                unsigned short* __restrict__ xs) {
  int row = blockIdx.x;
  int t = threadIdx.x;
  f32x4 v = ((const f32x4*)(x + (size_t)row * DIM_))[t];
  float sum = 0.f, ss = 0.f;
#pragma unroll
  for (int j = 0; j < 4; j++) { sum += v[j]; ss += v[j] * v[j]; }
#pragma unroll
  for (int off = 32; off >= 1; off >>= 1) {
    sum += __shfl_xor(sum, off);
    ss  += __shfl_xor(ss, off);
  }
  __shared__ float red[2][4];
  int wave = t >> 6, l = t & 63;
  if (l == 0) { red[0][wave] = sum; red[1][wave] = ss; }
  __syncthreads();
  sum = red[0][0] + red[0][1] + red[0][2] + red[0][3];
  ss  = red[1][0] + red[1][1] + red[1][2] + red[1][3];
  float mu = sum * (1.0f / DIM_);
  float var = ss * (1.0f / DIM_) - mu * mu;
  float rs = rsqrtf(var + 1e-5f);
  f32x4 g = ((const f32x4*)gamma)[t];
  f32x4 bb = ((const f32x4*)beta)[t];
  us4 o;
#pragma unroll
  for (int j = 0; j < 4; j++) o[j] = f2b((v[j] - mu) * rs * g[j] + bb[j]);
  int c0 = t * 4;
  if (c0 >= 512) {
    *(us4*)(xs + (size_t)row * DIM_ + c0) = o;
  } else {
    if (row + 1 < NTOK) *(us4*)(xs + (size_t)(row + 1) * DIM_ + c0) = o;
    if (row == 0) { us4 z = {0, 0, 0, 0}; *(us4*)(xs + c0) = z; }
  }
}

// ---------------------------------------------------------------------------
// f32 (R,C) -> bf16 (C,R) transpose; R,C multiples of 32. block (32,8)
// ---------------------------------------------------------------------------
__global__ __launch_bounds__(256) void transpose_f32_bf16(const float* __restrict__ in,
                                                          unsigned short* __restrict__ out,
                                                          int R, int C) {
  __shared__ unsigned short tile[32][33];
  int bx = blockIdx.x * 32, by = blockIdx.y * 32;
  int tx = threadIdx.x, ty = threadIdx.y;
#pragma unroll
  for (int i = 0; i < 32; i += 8) tile[ty + i][tx] = f2b(in[(size_t)(by + ty + i) * C + bx + tx]);
  __syncthreads();
#pragma unroll
  for (int i = 0; i < 32; i += 8) out[(size_t)(bx + ty + i) * R + by + tx] = tile[tx][ty + i];
}

// ---------------------------------------------------------------------------
// Pipelined NT GEMM (p8 core): C[M,N] = A[M,K] @ Bt[N,K]^T.
// BM=BN=256, BK=64, 512 thr (8 waves 2Mx4N). 2-slot LDS dbuf (128 KiB).
// Per K-tile: 4 phases x 16 MFMA, staging spread across phases, counted
// vmcnt(2) (retires exactly tile kt's 8 loads), barrier A + barrier B.
// NOTE: __launch_bounds__(512,2) REQUIRED — acc[8][4] = 128 unified regs;
// min-4-waves/EU bound spills the accumulator (round 7: 8x slower).
// MODE 0: RoPE epilogue -> qh/kh (lane-quad transpose, us4) + vt (lane-pair
// shfl RoPE, direct-transposed us4). MODE 1: f32 C + bias.
// ---------------------------------------------------------------------------
template <int MODE>
__global__ __launch_bounds__(512, 2) void gemm_p10(const unsigned short* __restrict__ A,
                                                   const unsigned short* __restrict__ Bt,
                                                   void* __restrict__ Cv,
                                                   const float* __restrict__ bias,
                                                   const float* __restrict__ sinp,
                                                   const float* __restrict__ cosp,
                                                   unsigned short* __restrict__ qh,
                                                   unsigned short* __restrict__ kh,
                                                   unsigned short* __restrict__ vt,
                                                   int M, int N, int K) {
  __shared__ __align__(16) char lds[131072];   // slot s: A at s*65536, B at +32768
  int t = threadIdx.x;
  int l = t & 63, lg = l >> 4, ll = l & 15;
  int wave = t >> 6;
  int wm = wave >> 2, wn = wave & 3;

  // XCD-bijective flat block swizzle (nwg % 8 == 0 for all our grids)
  int nbx = gridDim.x;
  int nwg = nbx * gridDim.y;
  int flat = blockIdx.y * nbx + blockIdx.x;
  int swz = (flat & 7) * (nwg >> 3) + (flat >> 3);
  int m0 = (swz / nbx) * 256, n0 = (swz % nbx) * 256;

  const f32x4 fz = {0.f, 0.f, 0.f, 0.f};
  f32x4 acc[8][4];
#pragma unroll
  for (int m = 0; m < 8; m++)
#pragma unroll
    for (int n = 0; n < 4; n++) acc[m][n] = fz;

  // staging: issue j covers rows j*64 + (t>>3), unit (t&7)^(row&7); 8KB/issue
  int srow = t >> 3;                           // 0..63
  int sunit = (t & 7) ^ (srow & 7);            // pre-swizzled source 16B-unit
  const unsigned short* gA = A + (size_t)(m0 + srow) * K + sunit * 8;
  const unsigned short* gB = Bt + (size_t)(n0 + srow) * K + sunit * 8;
  int t16 = t * 16;
  int nk = K >> 6;

  // prologue: stage tile 0 into slot 0 (8 issues)
#pragma unroll
  for (int j = 0; j < 4; j++) {
    gload_lds16(gA + (size_t)(j * 64) * K, lds + j * 8192 + t16);
    gload_lds16(gB + (size_t)(j * 64) * K, lds + 32768 + j * 8192 + t16);
  }

  for (int kt = 0; kt < nk - 1; ++kt) {
    const char* sa = lds + (kt & 1) * 65536;
    const char* sb = sa + 32768;
    char* dA = lds + ((kt + 1) & 1) * 65536;
    char* dB = dA + 32768;
    const unsigned short* nA = gA + (kt + 1) * 64;
    const unsigned short* nB = gB + (kt + 1) * 64;

    // pre-gate: stage A j0,j1 of tile kt+1 (slot readers done at prev barrier B)
    gload_lds16(nA, dA + t16);
    gload_lds16(nA + (size_t)64 * K, dA + 8192 + t16);
    asm volatile("s_waitcnt vmcnt(2)" ::: "memory");  // tile kt's 8 loads landed
    __builtin_amdgcn_sched_barrier(0);
    __builtin_amdgcn_s_barrier();                     // barrier A: data ready
    __builtin_amdgcn_sched_barrier(0);

    s8 bf[4];
#pragma unroll
    for (int p = 0; p < 4; ++p) {
      const int qm = p & 1, kk = p >> 1;
      s8 af[4];
#pragma unroll
      for (int m = 0; m < 4; m++) {
        int r = wm * 128 + qm * 64 + m * 16 + ll;
        af[m] = *(const s8*)(sa + r * 128 + (((kk * 4 + lg) ^ (r & 7)) << 4));
      }
      if (qm == 0) {
#pragma unroll
        for (int n = 0; n < 4; n++) {
          int r = wn * 64 + n * 16 + ll;
          bf[n] = *(const s8*)(sb + r * 128 + (((kk * 4 + lg) ^ (r & 7)) << 4));
        }
      }
      if (p == 0) {
        gload_lds16(nA + (size_t)128 * K, dA + 16384 + t16);
        gload_lds16(nA + (size_t)192 * K, dA + 24576 + t16);
      } else if (p == 1) {
        gload_lds16(nB, dB + t16);
        gload_lds16(nB + (size_t)64 * K, dB + 8192 + t16);
      } else if (p == 2) {
        gload_lds16(nB + (size_t)128 * K, dB + 16384 + t16);
        gload_lds16(nB + (size_t)192 * K, dB + 24576 + t16);
      }
      __builtin_amdgcn_s_setprio(1);
#pragma unroll
      for (int m = 0; m < 4; m++)
#pragma unroll
        for (int n = 0; n < 4; n++)
          acc[qm * 4 + m][n] =
              __builtin_amdgcn_mfma_f32_16x16x32_bf16(af[m], bf[n], acc[qm * 4 + m][n], 0, 0, 0);
      __builtin_amdgcn_s_setprio(0);
    }
    __builtin_amdgcn_sched_barrier(0);
    __builtin_amdgcn_s_barrier();   // barrier B: all reads of slot kt done
  }

  // final K-tile: no staging
  {
    int kt = nk - 1;
    const char* sa = lds + (kt & 1) * 65536;
    const char* sb = sa + 32768;
    asm volatile("s_waitcnt vmcnt(0)" ::: "memory");
    __builtin_amdgcn_sched_barrier(0);
    __builtin_amdgcn_s_barrier();
    __builtin_amdgcn_sched_barrier(0);
    s8 bf[4];
#pragma unroll
    for (int p = 0; p < 4; ++p) {
      const int qm = p & 1, kk = p >> 1;
      s8 af[4];
#pragma unroll
      for (int m = 0; m < 4; m++) {
        int r = wm * 128 + qm * 64 + m * 16 + ll;
        af[m] = *(const s8*)(sa + r * 128 + (((kk * 4 + lg) ^ (r & 7)) << 4));
      }
      if (qm == 0) {
#pragma unroll
        for (int n = 0; n < 4; n++) {
          int r = wn * 64 + n * 16 + ll;
          bf[n] = *(const s8*)(sb + r * 128 + (((kk * 4 + lg) ^ (r & 7)) << 4));
        }
      }
#pragma unroll
      for (int m = 0; m < 4; m++)
#pragma unroll
        for (int n = 0; n < 4; n++)
          acc[qm * 4 + m][n] =
              __builtin_amdgcn_mfma_f32_16x16x32_bf16(af[m], bf[n], acc[qm * 4 + m][n], 0, 0, 0);
    }
  }

  if (MODE == 0) {
    int third = n0 >> 9;  // block-uniform: 0=q, 1=k, 2=v
    if (third == 2) {
      // v: pre-transpose each lane holds rows lg*4..+3 (tokens) of col d.
      // RoPE partner (d^1) is lane ll^1 -> one shfl_xor per element.
      bool odd = (ll & 1) != 0;
#pragma unroll
      for (int m = 0; m < 8; m++) {
        int row0 = m0 + wm * 128 + m * 16 + lg * 4;
#pragma unroll
        for (int n = 0; n < 4; n++) {
          int cit = (n0 - 1024) + wn * 64 + n * 16 + ll;
          int head = cit >> 6, d = cit & 63;
          us4 st;
#pragma unroll
          for (int r = 0; r < 4; r++) {
            float v = acc[m][n][r];
            float p = __shfl_xor(v, 1);
            float sn = sinp[(size_t)(row0 + r) * 64 + d];
            float cs = cosp[(size_t)(row0 + r) * 64 + d];
            st[r] = f2b(odd ? (v * cs + p * sn) : (v * cs - p * sn));
          }
          *(us4*)(vt + ((size_t)head * 64 + d) * NTOK + row0) = st;
        }
      }
    } else {
      // q/k: 4x4 lane-quad transpose -> lane holds (row = lg*4+b, cols q*4..+3);
      // RoPE pairs lane-local; coalesced us4 stores.
      int b = ll & 3, q = ll >> 2;
      bool bo1 = (b & 1) != 0, bo2 = (b & 2) != 0;
#pragma unroll
      for (int m = 0; m < 8; m++) {
        int row = m0 + wm * 128 + m * 16 + lg * 4 + b;  // token
#pragma unroll
        for (int n = 0; n < 4; n++) {
          float v0 = acc[m][n][0], v1 = acc[m][n][1], v2 = acc[m][n][2], v3 = acc[m][n][3];
          float x0 = __shfl_xor(v1, 1);
          float x1 = __shfl_xor(v0, 1);
          float x2 = __shfl_xor(v3, 1);
          float x3 = __shfl_xor(v2, 1);
          float u0 = bo1 ? x0 : v0;
          float u1 = bo1 ? v1 : x1;
          float u2 = bo1 ? x2 : v2;
          float u3 = bo1 ? v3 : x3;
          float y0 = __shfl_xor(u2, 2);
          float y1 = __shfl_xor(u3, 2);
          float y2 = __shfl_xor(u0, 2);
          float y3 = __shfl_xor(u1, 2);
          float w0 = bo2 ? y0 : u0;
          float w1 = bo2 ? y1 : u1;
          float w2 = bo2 ? u2 : y2;
          float w3 = bo2 ? u3 : y3;
          int cb = n0 + wn * 64 + n * 16 + q * 4;
          int cit = cb & 511;
          int head = cit >> 6, d0 = cit & 63;
          f32x4 s4 = *(const f32x4*)(sinp + (size_t)row * 64 + d0);
          f32x4 c4 = *(const f32x4*)(cosp + (size_t)row * 64 + d0);
          us4 st;
          st[0] = f2b(w0 * c4[0] - w1 * s4[0]);
          st[1] = f2b(w1 * c4[1] + w0 * s4[1]);
          st[2] = f2b(w2 * c4[2] - w3 * s4[2]);
          st[3] = f2b(w3 * c4[3] + w2 * s4[3]);
          if (third == 0) *(us4*)(qh + ((size_t)head * NTOK + row) * 64 + d0) = st;
          else            *(us4*)(kh + ((size_t)head * NTOK + row) * 64 + d0) = st;
        }
      }
    }
  } else {
#pragma unroll
    for (int n = 0; n < 4; n++) {
      int col = n0 + wn * 64 + n * 16 + ll;
      float bs = bias ? bias[col] : 0.0f;
#pragma unroll
      for (int m = 0; m < 8; m++) {
#pragma unroll
        for (int r = 0; r < 4; r++) {
          int row = m0 + wm * 128 + m * 16 + lg * 4 + r;
          ((float*)Cv)[(size_t)row * N + col] = acc[m][n][r] + bs;
        }
      }
    }
  }
}

// ---------------------------------------------------------------------------
// Windowed lookback attention, v4: 32x32 MFMA, swapped operands, K AND V
// double-buffered (one __syncthreads per chunk — its implicit vmcnt drain
// covers both DMAs issued a full chunk earlier).
// block = (half, window, head), 4 waves x 32 q-rows. 8 chunks of 64 keys.
// ---------------------------------------------------------------------------
__global__ __launch_bounds__(256, 4) void attn_kernel(const unsigned short* __restrict__ qh,
                                                      const unsigned short* __restrict__ kh,
                                                      const unsigned short* __restrict__ vt,
                                                      unsigned short* __restrict__ ao) {
  __shared__ char kbuf[2][8192];   // 64 keys x 128B, unit-swizzled by (row&7)
  __shared__ char vbuf[2][8192];   // 64 d x 128B (64 keys), unit-swizzled by (d&7)
  int half = blockIdx.x, w = blockIdx.y, h = blockIdx.z;
  int t = threadIdx.x;
  int wave = t >> 6, l = t & 63;
  int l31 = l & 31, hi = l >> 5;
  const unsigned short* qb = qh + (size_t)h * NTOK * 64;
  const unsigned short* kb = kh + (size_t)h * NTOK * 64;
  const unsigned short* vb = vt + (size_t)h * 64 * NTOK;

  int qw = half * 128 + wave * 32 + l31;   // q within window
  int qn = w * 256 + qw;                   // global token
  s8 qf[4];
#pragma unroll
  for (int dht = 0; dht < 4; dht++)
    qf[dht] = *(const s8*)(qb + (size_t)qn * 64 + dht * 16 + hi * 8);

  f32x16 o0 = {}, o1 = {};
  float dsum = (w == 0) ? 128.f : 0.f;     // 256 zero-keys -> exp(0)=1, split across hi halves
  int n0 = w * 256 - 256;
  int c0 = (w == 0) ? 4 : 0;

  int srow = wave * 16 + (l >> 3);
  int sunit = l & 7;

  // prologue: stage K(c0) and V(c0)
  {
    const unsigned short* g = kb + (size_t)(n0 + c0 * 64 + srow) * 64 + ((sunit ^ (srow & 7)) * 8);
    gload_lds16(g, kbuf[c0 & 1] + wave * 2048);
    gload_lds16(g + 8 * 64, kbuf[c0 & 1] + wave * 2048 + 1024);
    const unsigned short* gv = vb + (size_t)srow * NTOK + (n0 + c0 * 64) + ((sunit ^ (srow & 7)) * 8);
    gload_lds16(gv, vbuf[c0 & 1] + wave * 2048);
    gload_lds16(gv + (size_t)8 * NTOK, vbuf[c0 & 1] + wave * 2048 + 1024);
  }
  __syncthreads();

  for (int c = c0; c < 8; ++c) {
    int cb = n0 + c * 64;
    // stage K(c+1), V(c+1) into opposite slots
    if (c < 7) {
      const unsigned short* g = kb + (size_t)(cb + 64 + srow) * 64 + ((sunit ^ (srow & 7)) * 8);
      gload_lds16(g, kbuf[(c + 1) & 1] + wave * 2048);
      gload_lds16(g + 8 * 64, kbuf[(c + 1) & 1] + wave * 2048 + 1024);
      const unsigned short* gv = vb + (size_t)srow * NTOK + (cb + 64) + ((sunit ^ (srow & 7)) * 8);
      gload_lds16(gv, vbuf[(c + 1) & 1] + wave * 2048);
      gload_lds16(gv + (size_t)8 * NTOK, vbuf[(c + 1) & 1] + wave * 2048 + 1024);
    }

    // QK^T (swapped): S^T tiles, 64 keys x 32 q
    f32x16 s[2] = {{}, {}};
    const char* kl = kbuf[c & 1];
#pragma unroll
    for (int kt = 0; kt < 2; kt++) {
#pragma unroll
      for (int dht = 0; dht < 4; dht++) {
        int row = kt * 32 + l31;
        int unit = (dht * 2 + hi) ^ (row & 7);
        s8 kf = *(const s8*)(kl + row * 128 + unit * 16);
        s[kt] = __builtin_amdgcn_mfma_f32_32x32x16_bf16(kf, qf[dht], s[kt], 0, 0, 0);
      }
    }

    // masked exp (no max-sub) + denominator + pack to bf16 pairs
    unsigned P0[2][4], P1[2][4];
#pragma unroll
    for (int kt = 0; kt < 2; kt++) {
#pragma unroll
      for (int r = 0; r < 16; r++) {
        int j = c * 64 + kt * 32 + (r & 3) + 8 * (r >> 2) + hi * 4;
        float e = (j <= qw + 256) ? __expf(s[kt][r] * 0.125f) : 0.f;
        s[kt][r] = e;
        dsum += e;
      }
#pragma unroll
      for (int j2 = 0; j2 < 4; j2++) {
        P0[kt][j2] = pk2(s[kt][j2 * 4 + 0], s[kt][j2 * 4 + 1]);
        P1[kt][j2] = pk2(s[kt][j2 * 4 + 2], s[kt][j2 * 4 + 3]);
      }
    }

    // PV (swapped): O^T += V^T(chunk) . P^T(chunk); V from vbuf[c&1]
    const char* vl = vbuf[c & 1];
#pragma unroll
    for (int tt = 0; tt < 4; tt++) {
      int kt = tt >> 1, ss = tt & 1;
      unsigned a = P0[kt][2 * ss], b = P1[kt][2 * ss];
      unsigned cx = P0[kt][2 * ss + 1], dx = P1[kt][2 * ss + 1];
      asm volatile("v_permlane32_swap_b32 %0, %1" : "+v"(a), "+v"(cx));
      asm volatile("v_permlane32_swap_b32 %0, %1" : "+v"(b), "+v"(dx));
      s8 pf = mk_s8(a, b, cx, dx);
      {
        int row = l31;
        int unit = (tt * 2 + hi) ^ (row & 7);
        s8 vf = *(const s8*)(vl + row * 128 + unit * 16);
        o0 = __builtin_amdgcn_mfma_f32_32x32x16_bf16(vf, pf, o0, 0, 0, 0);
      }
      {
        int row = 32 + l31;
        int unit = (tt * 2 + hi) ^ (row & 7);
        s8 vf = *(const s8*)(vl + row * 128 + unit * 16);
        o1 = __builtin_amdgcn_mfma_f32_32x32x16_bf16(vf, pf, o1, 0, 0, 0);
      }
    }
    __syncthreads();   // drains this chunk's DMAs; releases slot c&1 for c+2
  }

  dsum += __shfl_xor(dsum, 32);
  float inv = 1.f / dsum;

  unsigned short* orow = ao + (size_t)qn * INNER_ + h * 64;
#pragma unroll
  for (int g = 0; g < 4; g++) {
    us4 st0, st1;
#pragma unroll
    for (int rr = 0; rr < 4; rr++) {
      st0[rr] = f2b(o0[g * 4 + rr] * inv);
      st1[rr] = f2b(o1[g * 4 + rr] * inv);
    }
    *(us4*)(orow + g * 8 + hi * 4) = st0;
    *(us4*)(orow + 32 + g * 8 + hi * 4) = st1;
  }
}

// ---------------------------------------------------------------------------
extern "C" void kernel_launch(void* const* d_in, const int* in_sizes, int n_in,
                              void* d_out, int out_size, void* d_ws, size_t ws_size,
                              hipStream_t stream) {
  const float* x     = (const float*)d_in[0];
  const float* sin_  = (const float*)d_in[1];
  const float* cos_  = (const float*)d_in[2];
  const float* gamma = (const float*)d_in[3];
  const float* beta  = (const float*)d_in[4];
  const float* w_qkv = (const float*)d_in[5];
  const float* w_out = (const float*)d_in[6];
  const float* b_out = (const float*)d_in[7];

  // ws layout (bytes). total needed = 171,966,464
  char* ws = (char*)d_ws;
  const size_t OFF_WQT = 0;                    // 1536*1024*2 = 3,145,728
  const size_t OFF_WOT = 3145728;              // 1024*512*2  = 1,048,576
  const size_t OFF_XS  = 4194304;              // 32768*1024*2 = 67,108,864 (xs; later ao)
  const size_t OFF_QH  = 71303168;             // 8*32768*64*2 = 33,554,432
  const size_t OFF_KH  = 104857600;            // 33,554,432
  const size_t OFF_VT  = 138412032;            // 8*64*32768*2 = 33,554,432
  const size_t NEEDED  = 171966464;
  if (ws_size < NEEDED) return;  // fail loudly (output stays poisoned)

  unsigned short* wqT = (unsigned short*)(ws + OFF_WQT);
  unsigned short* woT = (unsigned short*)(ws + OFF_WOT);
  unsigned short* xs  = (unsigned short*)(ws + OFF_XS);
  unsigned short* qh  = (unsigned short*)(ws + OFF_QH);
  unsigned short* kh  = (unsigned short*)(ws + OFF_KH);
  unsigned short* vt  = (unsigned short*)(ws + OFF_VT);
  unsigned short* ao  = xs;   // xs dead after gemm1; attn writes ao here

  transpose_f32_bf16<<<dim3(1536 / 32, 1024 / 32), dim3(32, 8), 0, stream>>>(w_qkv, wqT, 1024, 1536);
  transpose_f32_bf16<<<dim3(1024 / 32, 512 / 32), dim3(32, 8), 0, stream>>>(w_out, woT, 512, 1024);
  ln_shift<<<NTOK, 256, 0, stream>>>(x, gamma, beta, xs);
  gemm_p10<0><<<dim3(1536 / 256, NTOK / 256), 512, 0, stream>>>(
      xs, wqT, nullptr, nullptr, sin_, cos_, qh, kh, vt, NTOK, 1536, 1024);
  attn_kernel<<<dim3(2, NWIN_, HEADS_), 256, 0, stream>>>(qh, kh, vt, ao);
  gemm_p10<1><<<dim3(1024 / 256, NTOK / 256), 512, 0, stream>>>(
      ao, woT, (void*)d_out, b_out, nullptr, nullptr, nullptr, nullptr, nullptr, NTOK, 1024, 512);
}

// Round 17
// 305.676 us; speedup vs baseline: 1.6161x; 1.0285x over previous
//
#include <hip/hip_runtime.h>

typedef __attribute__((ext_vector_type(4))) unsigned short us4;
typedef __attribute__((ext_vector_type(8))) unsigned short us8;
typedef __attribute__((ext_vector_type(8))) short s8;      // MFMA A/B fragment (8 bf16)
typedef __attribute__((ext_vector_type(4))) float f32x4;   // 16x16 MFMA acc / float4
typedef __attribute__((ext_vector_type(16))) float f32x16; // 32x32 MFMA acc

#define NTOK 32768
#define DIM_ 1024
#define HEADS_ 8
#define DH_ 64
#define WS_ 256
#define NWIN_ 128
#define INNER_ 512

__device__ __forceinline__ float b2f(unsigned short u) {
  union { unsigned u; float f; } x; x.u = ((unsigned)u) << 16; return x.f;
}
__device__ __forceinline__ unsigned short f2b(float f) {
  union { float f; unsigned u; } x; x.f = f;
  unsigned r = x.u + 0x7FFFu + ((x.u >> 16) & 1u);  // RNE
  return (unsigned short)(r >> 16);
}
__device__ __forceinline__ unsigned cvtpk(float a, float b) {
  unsigned r;
  asm("v_cvt_pk_bf16_f32 %0, %1, %2" : "=v"(r) : "v"(a), "v"(b));  // RNE, = pk2
  return r;
}
__device__ __forceinline__ s8 mk_s8(unsigned w0, unsigned w1, unsigned w2, unsigned w3) {
  union { unsigned u[4]; s8 v; } x;
  x.u[0] = w0; x.u[1] = w1; x.u[2] = w2; x.u[3] = w3;
  return x.v;
}

// global -> LDS direct DMA, 16B per lane. LDS dest = wave-uniform base + lane*16.
__device__ __forceinline__ void gload_lds16(const unsigned short* g, void* l) {
  __builtin_amdgcn_global_load_lds((const __attribute__((address_space(1))) void*)g,
                                   (__attribute__((address_space(3))) void*)l, 16, 0, 0);
}

// ---------------------------------------------------------------------------
// LayerNorm (f32 in) + half-row shift -> bf16 xs.
// ---------------------------------------------------------------------------
__global__ __launch_bounds__(256) void ln_shift(const float* __restrict__ x,
                                                const float* __restrict__ gamma,
                                                const float* __restrict__ beta,
                                                unsigned short* __restrict__ xs) {
  int row = blockIdx.x;
  int t = threadIdx.x;
  f32x4 v = ((const f32x4*)(x + (size_t)row * DIM_))[t];
  float sum = 0.f, ss = 0.f;
#pragma unroll
  for (int j = 0; j < 4; j++) { sum += v[j]; ss += v[j] * v[j]; }
#pragma unroll
  for (int off = 32; off >= 1; off >>= 1) {
    sum += __shfl_xor(sum, off);
    ss  += __shfl_xor(ss, off);
  }
  __shared__ float red[2][4];
  int wave = t >> 6, l = t & 63;
  if (l == 0) { red[0][wave] = sum; red[1][wave] = ss; }
  __syncthreads();
  sum = red[0][0] + red[0][1] + red[0][2] + red[0][3];
  ss  = red[1][0] + red[1][1] + red[1][2] + red[1][3];
  float mu = sum * (1.0f / DIM_);
  float var = ss * (1.0f / DIM_) - mu * mu;
  float rs = rsqrtf(var + 1e-5f);
  f32x4 g = ((const f32x4*)gamma)[t];
  f32x4 bb = ((const f32x4*)beta)[t];
  us4 o;
#pragma unroll
  for (int j = 0; j < 4; j++) o[j] = f2b((v[j] - mu) * rs * g[j] + bb[j]);
  int c0 = t * 4;
  if (c0 >= 512) {
    *(us4*)(xs + (size_t)row * DIM_ + c0) = o;
  } else {
    if (row + 1 < NTOK) *(us4*)(xs + (size_t)(row + 1) * DIM_ + c0) = o;
    if (row == 0) { us4 z = {0, 0, 0, 0}; *(us4*)(xs + c0) = z; }
  }
}

// ---------------------------------------------------------------------------
// f32 (R,C) -> bf16 (C,R) transpose; R,C multiples of 32. block (32,8)
// ---------------------------------------------------------------------------
__global__ __launch_bounds__(256) void transpose_f32_bf16(const float* __restrict__ in,
                                                          unsigned short* __restrict__ out,
                                                          int R, int C) {
  __shared__ unsigned short tile[32][33];
  int bx = blockIdx.x * 32, by = blockIdx.y * 32;
  int tx = threadIdx.x, ty = threadIdx.y;
#pragma unroll
  for (int i = 0; i < 32; i += 8) tile[ty + i][tx] = f2b(in[(size_t)(by + ty + i) * C + bx + tx]);
  __syncthreads();
#pragma unroll
  for (int i = 0; i < 32; i += 8) out[(size_t)(bx + ty + i) * R + by + tx] = tile[tx][ty + i];
}

// ---------------------------------------------------------------------------
// Pipelined NT GEMM (p8 core): C[M,N] = A[M,K] @ Bt[N,K]^T.
// BM=BN=256, BK=64, 512 thr (8 waves 2Mx4N). 2-slot LDS dbuf (128 KiB).
// Per K-tile: 4 phases x 16 MFMA, staging spread across phases, counted
// vmcnt(2) (retires exactly tile kt's 8 loads), barrier A + barrier B.
// NOTE: __launch_bounds__(512,2) REQUIRED — acc[8][4] = 128 unified regs;
// min-4-waves/EU bound spills the accumulator (round 7: 8x slower).
// MODE 0: RoPE epilogue -> qh/kh (lane-quad transpose, us4; q PRE-SCALED by
// 0.125 = exact 2^-3, folds the 1/sqrt(d) into q so attn skips 256 muls) +
// vt (lane-pair shfl RoPE, direct-transposed us4). MODE 1: f32 C + bias.
// ---------------------------------------------------------------------------
template <int MODE>
__global__ __launch_bounds__(512, 2) void gemm_p10(const unsigned short* __restrict__ A,
                                                   const unsigned short* __restrict__ Bt,
                                                   void* __restrict__ Cv,
                                                   const float* __restrict__ bias,
                                                   const float* __restrict__ sinp,
                                                   const float* __restrict__ cosp,
                                                   unsigned short* __restrict__ qh,
                                                   unsigned short* __restrict__ kh,
                                                   unsigned short* __restrict__ vt,
                                                   int M, int N, int K) {
  __shared__ __align__(16) char lds[131072];   // slot s: A at s*65536, B at +32768
  int t = threadIdx.x;
  int l = t & 63, lg = l >> 4, ll = l & 15;
  int wave = t >> 6;
  int wm = wave >> 2, wn = wave & 3;

  // XCD-bijective flat block swizzle (nwg % 8 == 0 for all our grids)
  int nbx = gridDim.x;
  int nwg = nbx * gridDim.y;
  int flat = blockIdx.y * nbx + blockIdx.x;
  int swz = (flat & 7) * (nwg >> 3) + (flat >> 3);
  int m0 = (swz / nbx) * 256, n0 = (swz % nbx) * 256;

  const f32x4 fz = {0.f, 0.f, 0.f, 0.f};
  f32x4 acc[8][4];
#pragma unroll
  for (int m = 0; m < 8; m++)
#pragma unroll
    for (int n = 0; n < 4; n++) acc[m][n] = fz;

  // staging: issue j covers rows j*64 + (t>>3), unit (t&7)^(row&7); 8KB/issue
  int srow = t >> 3;                           // 0..63
  int sunit = (t & 7) ^ (srow & 7);            // pre-swizzled source 16B-unit
  const unsigned short* gA = A + (size_t)(m0 + srow) * K + sunit * 8;
  const unsigned short* gB = Bt + (size_t)(n0 + srow) * K + sunit * 8;
  int t16 = t * 16;
  int nk = K >> 6;

  // prologue: stage tile 0 into slot 0 (8 issues)
#pragma unroll
  for (int j = 0; j < 4; j++) {
    gload_lds16(gA + (size_t)(j * 64) * K, lds + j * 8192 + t16);
    gload_lds16(gB + (size_t)(j * 64) * K, lds + 32768 + j * 8192 + t16);
  }

  for (int kt = 0; kt < nk - 1; ++kt) {
    const char* sa = lds + (kt & 1) * 65536;
    const char* sb = sa + 32768;
    char* dA = lds + ((kt + 1) & 1) * 65536;
    char* dB = dA + 32768;
    const unsigned short* nA = gA + (kt + 1) * 64;
    const unsigned short* nB = gB + (kt + 1) * 64;

    // pre-gate: stage A j0,j1 of tile kt+1 (slot readers done at prev barrier B)
    gload_lds16(nA, dA + t16);
    gload_lds16(nA + (size_t)64 * K, dA + 8192 + t16);
    asm volatile("s_waitcnt vmcnt(2)" ::: "memory");  // tile kt's 8 loads landed
    __builtin_amdgcn_sched_barrier(0);
    __builtin_amdgcn_s_barrier();                     // barrier A: data ready
    __builtin_amdgcn_sched_barrier(0);

    s8 bf[4];
#pragma unroll
    for (int p = 0; p < 4; ++p) {
      const int qm = p & 1, kk = p >> 1;
      s8 af[4];
#pragma unroll
      for (int m = 0; m < 4; m++) {
        int r = wm * 128 + qm * 64 + m * 16 + ll;
        af[m] = *(const s8*)(sa + r * 128 + (((kk * 4 + lg) ^ (r & 7)) << 4));
      }
      if (qm == 0) {
#pragma unroll
        for (int n = 0; n < 4; n++) {
          int r = wn * 64 + n * 16 + ll;
          bf[n] = *(const s8*)(sb + r * 128 + (((kk * 4 + lg) ^ (r & 7)) << 4));
        }
      }
      if (p == 0) {
        gload_lds16(nA + (size_t)128 * K, dA + 16384 + t16);
        gload_lds16(nA + (size_t)192 * K, dA + 24576 + t16);
      } else if (p == 1) {
        gload_lds16(nB, dB + t16);
        gload_lds16(nB + (size_t)64 * K, dB + 8192 + t16);
      } else if (p == 2) {
        gload_lds16(nB + (size_t)128 * K, dB + 16384 + t16);
        gload_lds16(nB + (size_t)192 * K, dB + 24576 + t16);
      }
      __builtin_amdgcn_s_setprio(1);
#pragma unroll
      for (int m = 0; m < 4; m++)
#pragma unroll
        for (int n = 0; n < 4; n++)
          acc[qm * 4 + m][n] =
              __builtin_amdgcn_mfma_f32_16x16x32_bf16(af[m], bf[n], acc[qm * 4 + m][n], 0, 0, 0);
      __builtin_amdgcn_s_setprio(0);
    }
    __builtin_amdgcn_sched_barrier(0);
    __builtin_amdgcn_s_barrier();   // barrier B: all reads of slot kt done
  }

  // final K-tile: no staging
  {
    int kt = nk - 1;
    const char* sa = lds + (kt & 1) * 65536;
    const char* sb = sa + 32768;
    asm volatile("s_waitcnt vmcnt(0)" ::: "memory");
    __builtin_amdgcn_sched_barrier(0);
    __builtin_amdgcn_s_barrier();
    __builtin_amdgcn_sched_barrier(0);
    s8 bf[4];
#pragma unroll
    for (int p = 0; p < 4; ++p) {
      const int qm = p & 1, kk = p >> 1;
      s8 af[4];
#pragma unroll
      for (int m = 0; m < 4; m++) {
        int r = wm * 128 + qm * 64 + m * 16 + ll;
        af[m] = *(const s8*)(sa + r * 128 + (((kk * 4 + lg) ^ (r & 7)) << 4));
      }
      if (qm == 0) {
#pragma unroll
        for (int n = 0; n < 4; n++) {
          int r = wn * 64 + n * 16 + ll;
          bf[n] = *(const s8*)(sb + r * 128 + (((kk * 4 + lg) ^ (r & 7)) << 4));
        }
      }
#pragma unroll
      for (int m = 0; m < 4; m++)
#pragma unroll
        for (int n = 0; n < 4; n++)
          acc[qm * 4 + m][n] =
              __builtin_amdgcn_mfma_f32_16x16x32_bf16(af[m], bf[n], acc[qm * 4 + m][n], 0, 0, 0);
    }
  }

  if (MODE == 0) {
    int third = n0 >> 9;  // block-uniform: 0=q, 1=k, 2=v
    if (third == 2) {
      // v: pre-transpose each lane holds rows lg*4..+3 (tokens) of col d.
      // RoPE partner (d^1) is lane ll^1 -> one shfl_xor per element.
      bool odd = (ll & 1) != 0;
#pragma unroll
      for (int m = 0; m < 8; m++) {
        int row0 = m0 + wm * 128 + m * 16 + lg * 4;
#pragma unroll
        for (int n = 0; n < 4; n++) {
          int cit = (n0 - 1024) + wn * 64 + n * 16 + ll;
          int head = cit >> 6, d = cit & 63;
          us4 st;
#pragma unroll
          for (int r = 0; r < 4; r++) {
            float v = acc[m][n][r];
            float p = __shfl_xor(v, 1);
            float sn = sinp[(size_t)(row0 + r) * 64 + d];
            float cs = cosp[(size_t)(row0 + r) * 64 + d];
            st[r] = f2b(odd ? (v * cs + p * sn) : (v * cs - p * sn));
          }
          *(us4*)(vt + ((size_t)head * 64 + d) * NTOK + row0) = st;
        }
      }
    } else {
      // q/k: 4x4 lane-quad transpose -> lane holds (row = lg*4+b, cols q*4..+3);
      // RoPE pairs lane-local; coalesced us4 stores. q pre-scaled by 0.125
      // (exact 2^-3: bit-identical to scaling S post-MFMA).
      int b = ll & 3, q = ll >> 2;
      bool bo1 = (b & 1) != 0, bo2 = (b & 2) != 0;
      float sc = (third == 0) ? 0.125f : 1.0f;
#pragma unroll
      for (int m = 0; m < 8; m++) {
        int row = m0 + wm * 128 + m * 16 + lg * 4 + b;  // token
#pragma unroll
        for (int n = 0; n < 4; n++) {
          float v0 = acc[m][n][0], v1 = acc[m][n][1], v2 = acc[m][n][2], v3 = acc[m][n][3];
          float x0 = __shfl_xor(v1, 1);
          float x1 = __shfl_xor(v0, 1);
          float x2 = __shfl_xor(v3, 1);
          float x3 = __shfl_xor(v2, 1);
          float u0 = bo1 ? x0 : v0;
          float u1 = bo1 ? v1 : x1;
          float u2 = bo1 ? x2 : v2;
          float u3 = bo1 ? v3 : x3;
          float y0 = __shfl_xor(u2, 2);
          float y1 = __shfl_xor(u3, 2);
          float y2 = __shfl_xor(u0, 2);
          float y3 = __shfl_xor(u1, 2);
          float w0 = bo2 ? y0 : u0;
          float w1 = bo2 ? y1 : u1;
          float w2 = bo2 ? u2 : y2;
          float w3 = bo2 ? u3 : y3;
          int cb = n0 + wn * 64 + n * 16 + q * 4;
          int cit = cb & 511;
          int head = cit >> 6, d0 = cit & 63;
          f32x4 s4 = *(const f32x4*)(sinp + (size_t)row * 64 + d0);
          f32x4 c4 = *(const f32x4*)(cosp + (size_t)row * 64 + d0);
          us4 st;
          st[0] = f2b((w0 * c4[0] - w1 * s4[0]) * sc);
          st[1] = f2b((w1 * c4[1] + w0 * s4[1]) * sc);
          st[2] = f2b((w2 * c4[2] - w3 * s4[2]) * sc);
          st[3] = f2b((w3 * c4[3] + w2 * s4[3]) * sc);
          if (third == 0) *(us4*)(qh + ((size_t)head * NTOK + row) * 64 + d0) = st;
          else            *(us4*)(kh + ((size_t)head * NTOK + row) * 64 + d0) = st;
        }
      }
    }
  } else {
#pragma unroll
    for (int n = 0; n < 4; n++) {
      int col = n0 + wn * 64 + n * 16 + ll;
      float bs = bias ? bias[col] : 0.0f;
#pragma unroll
      for (int m = 0; m < 8; m++) {
#pragma unroll
        for (int r = 0; r < 4; r++) {
          int row = m0 + wm * 128 + m * 16 + lg * 4 + r;
          ((float*)Cv)[(size_t)row * N + col] = acc[m][n][r] + bs;
        }
      }
    }
  }
}

// ---------------------------------------------------------------------------
// Windowed lookback attention, v5: 32x32 MFMA, swapped operands, K AND V
// double-buffered (one __syncthreads per chunk). q pre-scaled by 1/8 in
// gemm1 epilogue (no per-element scale here); P packing via
// v_cvt_pk_bf16_f32 (1 instr vs ~8 int-ALU ops per pair).
// block = (half, window, head), 4 waves x 32 q-rows. 8 chunks of 64 keys.
// ---------------------------------------------------------------------------
__global__ __launch_bounds__(256, 4) void attn_kernel(const unsigned short* __restrict__ qh,
                                                      const unsigned short* __restrict__ kh,
                                                      const unsigned short* __restrict__ vt,
                                                      unsigned short* __restrict__ ao) {
  __shared__ char kbuf[2][8192];   // 64 keys x 128B, unit-swizzled by (row&7)
  __shared__ char vbuf[2][8192];   // 64 d x 128B (64 keys), unit-swizzled by (d&7)
  int half = blockIdx.x, w = blockIdx.y, h = blockIdx.z;
  int t = threadIdx.x;
  int wave = t >> 6, l = t & 63;
  int l31 = l & 31, hi = l >> 5;
  const unsigned short* qb = qh + (size_t)h * NTOK * 64;
  const unsigned short* kb = kh + (size_t)h * NTOK * 64;
  const unsigned short* vb = vt + (size_t)h * 64 * NTOK;

  int qw = half * 128 + wave * 32 + l31;   // q within window
  int qn = w * 256 + qw;                   // global token
  s8 qf[4];
#pragma unroll
  for (int dht = 0; dht < 4; dht++)
    qf[dht] = *(const s8*)(qb + (size_t)qn * 64 + dht * 16 + hi * 8);

  f32x16 o0 = {}, o1 = {};
  float dsum = (w == 0) ? 128.f : 0.f;     // 256 zero-keys -> exp(0)=1, split across hi halves
  int n0 = w * 256 - 256;
  int c0 = (w == 0) ? 4 : 0;

  int srow = wave * 16 + (l >> 3);
  int sunit = l & 7;

  // prologue: stage K(c0) and V(c0)
  {
    const unsigned short* g = kb + (size_t)(n0 + c0 * 64 + srow) * 64 + ((sunit ^ (srow & 7)) * 8);
    gload_lds16(g, kbuf[c0 & 1] + wave * 2048);
    gload_lds16(g + 8 * 64, kbuf[c0 & 1] + wave * 2048 + 1024);
    const unsigned short* gv = vb + (size_t)srow * NTOK + (n0 + c0 * 64) + ((sunit ^ (srow & 7)) * 8);
    gload_lds16(gv, vbuf[c0 & 1] + wave * 2048);
    gload_lds16(gv + (size_t)8 * NTOK, vbuf[c0 & 1] + wave * 2048 + 1024);
  }
  __syncthreads();

  for (int c = c0; c < 8; ++c) {
    int cb = n0 + c * 64;
    // stage K(c+1), V(c+1) into opposite slots
    if (c < 7) {
      const unsigned short* g = kb + (size_t)(cb + 64 + srow) * 64 + ((sunit ^ (srow & 7)) * 8);
      gload_lds16(g, kbuf[(c + 1) & 1] + wave * 2048);
      gload_lds16(g + 8 * 64, kbuf[(c + 1) & 1] + wave * 2048 + 1024);
      const unsigned short* gv = vb + (size_t)srow * NTOK + (cb + 64) + ((sunit ^ (srow & 7)) * 8);
      gload_lds16(gv, vbuf[(c + 1) & 1] + wave * 2048);
      gload_lds16(gv + (size_t)8 * NTOK, vbuf[(c + 1) & 1] + wave * 2048 + 1024);
    }

    // QK^T (swapped): S^T tiles, 64 keys x 32 q (q already carries 1/8)
    f32x16 s[2] = {{}, {}};
    const char* kl = kbuf[c & 1];
#pragma unroll
    for (int kt = 0; kt < 2; kt++) {
#pragma unroll
      for (int dht = 0; dht < 4; dht++) {
        int row = kt * 32 + l31;
        int unit = (dht * 2 + hi) ^ (row & 7);
        s8 kf = *(const s8*)(kl + row * 128 + unit * 16);
        s[kt] = __builtin_amdgcn_mfma_f32_32x32x16_bf16(kf, qf[dht], s[kt], 0, 0, 0);
      }
    }

    // masked exp (no max-sub) + denominator + pack to bf16 via cvt_pk
    unsigned P0[2][4], P1[2][4];
#pragma unroll
    for (int kt = 0; kt < 2; kt++) {
#pragma unroll
      for (int r = 0; r < 16; r++) {
        int j = c * 64 + kt * 32 + (r & 3) + 8 * (r >> 2) + hi * 4;
        float e = (j <= qw + 256) ? __expf(s[kt][r]) : 0.f;
        s[kt][r] = e;
        dsum += e;
      }
#pragma unroll
      for (int j2 = 0; j2 < 4; j2++) {
        P0[kt][j2] = cvtpk(s[kt][j2 * 4 + 0], s[kt][j2 * 4 + 1]);
        P1[kt][j2] = cvtpk(s[kt][j2 * 4 + 2], s[kt][j2 * 4 + 3]);
      }
    }

    // PV (swapped): O^T += V^T(chunk) . P^T(chunk); V from vbuf[c&1]
    const char* vl = vbuf[c & 1];
#pragma unroll
    for (int tt = 0; tt < 4; tt++) {
      int kt = tt >> 1, ss = tt & 1;
      unsigned a = P0[kt][2 * ss], b = P1[kt][2 * ss];
      unsigned cx = P0[kt][2 * ss + 1], dx = P1[kt][2 * ss + 1];
      asm volatile("v_permlane32_swap_b32 %0, %1" : "+v"(a), "+v"(cx));
      asm volatile("v_permlane32_swap_b32 %0, %1" : "+v"(b), "+v"(dx));
      s8 pf = mk_s8(a, b, cx, dx);
      {
        int row = l31;
        int unit = (tt * 2 + hi) ^ (row & 7);
        s8 vf = *(const s8*)(vl + row * 128 + unit * 16);
        o0 = __builtin_amdgcn_mfma_f32_32x32x16_bf16(vf, pf, o0, 0, 0, 0);
      }
      {
        int row = 32 + l31;
        int unit = (tt * 2 + hi) ^ (row & 7);
        s8 vf = *(const s8*)(vl + row * 128 + unit * 16);
        o1 = __builtin_amdgcn_mfma_f32_32x32x16_bf16(vf, pf, o1, 0, 0, 0);
      }
    }
    __syncthreads();   // drains this chunk's DMAs; releases slot c&1 for c+2
  }

  dsum += __shfl_xor(dsum, 32);
  float inv = 1.f / dsum;

  unsigned short* orow = ao + (size_t)qn * INNER_ + h * 64;
#pragma unroll
  for (int g = 0; g < 4; g++) {
    us4 st0, st1;
#pragma unroll
    for (int rr = 0; rr < 4; rr++) {
      st0[rr] = f2b(o0[g * 4 + rr] * inv);
      st1[rr] = f2b(o1[g * 4 + rr] * inv);
    }
    *(us4*)(orow + g * 8 + hi * 4) = st0;
    *(us4*)(orow + 32 + g * 8 + hi * 4) = st1;
  }
}

// ---------------------------------------------------------------------------
extern "C" void kernel_launch(void* const* d_in, const int* in_sizes, int n_in,
                              void* d_out, int out_size, void* d_ws, size_t ws_size,
                              hipStream_t stream) {
  const float* x     = (const float*)d_in[0];
  const float* sin_  = (const float*)d_in[1];
  const float* cos_  = (const float*)d_in[2];
  const float* gamma = (const float*)d_in[3];
  const float* beta  = (const float*)d_in[4];
  const float* w_qkv = (const float*)d_in[5];
  const float* w_out = (const float*)d_in[6];
  const float* b_out = (const float*)d_in[7];

  // ws layout (bytes). total needed = 171,966,464
  char* ws = (char*)d_ws;
  const size_t OFF_WQT = 0;                    // 1536*1024*2 = 3,145,728
  const size_t OFF_WOT = 3145728;              // 1024*512*2  = 1,048,576
  const size_t OFF_XS  = 4194304;              // 32768*1024*2 = 67,108,864 (xs; later ao)
  const size_t OFF_QH  = 71303168;             // 8*32768*64*2 = 33,554,432
  const size_t OFF_KH  = 104857600;            // 33,554,432
  const size_t OFF_VT  = 138412032;            // 8*64*32768*2 = 33,554,432
  const size_t NEEDED  = 171966464;
  if (ws_size < NEEDED) return;  // fail loudly (output stays poisoned)

  unsigned short* wqT = (unsigned short*)(ws + OFF_WQT);
  unsigned short* woT = (unsigned short*)(ws + OFF_WOT);
  unsigned short* xs  = (unsigned short*)(ws + OFF_XS);
  unsigned short* qh  = (unsigned short*)(ws + OFF_QH);
  unsigned short* kh  = (unsigned short*)(ws + OFF_KH);
  unsigned short* vt  = (unsigned short*)(ws + OFF_VT);
  unsigned short* ao  = xs;   // xs dead after gemm1; attn writes ao here

  transpose_f32_bf16<<<dim3(1536 / 32, 1024 / 32), dim3(32, 8), 0, stream>>>(w_qkv, wqT, 1024, 1536);
  transpose_f32_bf16<<<dim3(1024 / 32, 512 / 32), dim3(32, 8), 0, stream>>>(w_out, woT, 512, 1024);
  ln_shift<<<NTOK, 256, 0, stream>>>(x, gamma, beta, xs);
  gemm_p10<0><<<dim3(1536 / 256, NTOK / 256), 512, 0, stream>>>(
      xs, wqT, nullptr, nullptr, sin_, cos_, qh, kh, vt, NTOK, 1536, 1024);
  attn_kernel<<<dim3(2, NWIN_, HEADS_), 256, 0, stream>>>(qh, kh, vt, ao);
  gemm_p10<1><<<dim3(1024 / 256, NTOK / 256), 512, 0, stream>>>(
      ao, woT, (void*)d_out, b_out, nullptr, nullptr, nullptr, nullptr, nullptr, NTOK, 1024, 512);
}